// Round 2
// baseline (249.239 us; speedup 1.0000x reference)
//
#include <hip/hip_runtime.h>
#include <hip/hip_bf16.h>

// KroneckerAttention on MI355X.
// B=2,H=16 (BH=32), NQ=NK=4096, D=64, m=n=4, pq=pk=1024, c0=c1=2, scale=1/8.
// ws layout (floats): [0,512)   nsq[bh][gi][gj]   (norm^2 of w over pq)
//                     [512,8704) vsum[bh][gj][dd]

#define BH_TOT 32
#define SEQ    4096
#define DIM    64
#define PQ     1024

typedef __attribute__((ext_vector_type(8))) short bf16x8;
typedef __attribute__((ext_vector_type(4))) short bf16x4;
typedef __attribute__((ext_vector_type(4))) float f32x4;

__device__ __forceinline__ short f2bf(float x) {
    unsigned u = __float_as_uint(x);
    u = u + 0x7fffu + ((u >> 16) & 1u);   // RNE truncate to bf16
    return (short)(u >> 16);
}
__device__ __forceinline__ float bf2f(unsigned short h) {
    return __uint_as_float(((unsigned)h) << 16);
}

// ---------- prep: blocks [0,128) -> w-norms ; blocks [128,256) -> v_sum ----
__global__ __launch_bounds__(256) void prep_kernel(
    const float* __restrict__ query, const float* __restrict__ key,
    const float* __restrict__ value, float* __restrict__ ws)
{
    __shared__ float ksm[4][64];
    __shared__ float wsum[4][4];
    __shared__ float part[16][16][4];
    const int t = threadIdx.x;
    const int blk = blockIdx.x;
    if (blk < 128) {
        const int bh = blk >> 2, gi = blk & 3;
        // k_sample: first key of each key-group
        ksm[t >> 6][t & 63] = key[((size_t)bh * SEQ + (size_t)(t >> 6) * PQ) * DIM + (t & 63)];
        __syncthreads();
        const int c4 = t & 15;
        float k0[4], k1[4], k2[4], k3[4];
#pragma unroll
        for (int g = 0; g < 4; ++g) {
            k0[g] = ksm[g][c4 * 4 + 0]; k1[g] = ksm[g][c4 * 4 + 1];
            k2[g] = ksm[g][c4 * 4 + 2]; k3[g] = ksm[g][c4 * 4 + 3];
        }
        float acc[4] = {0.f, 0.f, 0.f, 0.f};
        const float4* qv = (const float4*)(query + ((size_t)bh * SEQ + (size_t)gi * PQ) * DIM);
        for (int it = 0; it < 64; ++it) {
            const int r = it * 16 + (t >> 4);
            float4 q = qv[r * 16 + c4];
#pragma unroll
            for (int g = 0; g < 4; ++g) {
                float p = q.x * k0[g] + q.y * k1[g] + q.z * k2[g] + q.w * k3[g];
                p += __shfl_xor(p, 1); p += __shfl_xor(p, 2);
                p += __shfl_xor(p, 4); p += __shfl_xor(p, 8);
                acc[g] += p * p;          // each row counted 16x; /16 at the end
            }
        }
#pragma unroll
        for (int g = 0; g < 4; ++g) {
            acc[g] += __shfl_xor(acc[g], 16);
            acc[g] += __shfl_xor(acc[g], 32);
        }
        if ((t & 63) == 0) {
#pragma unroll
            for (int g = 0; g < 4; ++g) wsum[t >> 6][g] = acc[g];
        }
        __syncthreads();
        if (t < 4) {
            float s = (wsum[0][t] + wsum[1][t] + wsum[2][t] + wsum[3][t]) * (1.0f / 16.0f);
            ws[bh * 16 + gi * 4 + t] = s;
        }
    } else {
        const int bh = (blk - 128) >> 2, gj = (blk - 128) & 3;
        const float4* vv = (const float4*)(value + ((size_t)bh * SEQ + (size_t)gj * PQ) * DIM);
        const int c4 = t & 15, rg = t >> 4;
        float a0 = 0.f, a1 = 0.f, a2 = 0.f, a3 = 0.f;
        for (int r = rg; r < 1024; r += 16) {
            float4 x = vv[r * 16 + c4];
            a0 += x.x; a1 += x.y; a2 += x.z; a3 += x.w;
        }
        part[rg][c4][0] = a0; part[rg][c4][1] = a1;
        part[rg][c4][2] = a2; part[rg][c4][3] = a3;
        __syncthreads();
        if (t < 64) {
            const int cc = t >> 2, comp = t & 3;
            float s = 0.f;
#pragma unroll
            for (int g = 0; g < 16; ++g) s += part[g][cc][comp];
            ws[512 + bh * 256 + gj * 64 + cc * 4 + comp] = s;
        }
    }
}

// ---------- main: fused central-group attention + Kronecker combine ----------
// grid = 512 (bh*16 + qtile), block = 256 (4 waves). Wave w owns value-group w.
__global__ __launch_bounds__(256, 2) void kattn_kernel(
    const float* __restrict__ query, const float* __restrict__ key,
    const float* __restrict__ value, const float* __restrict__ ws,
    float* __restrict__ out)
{
    __shared__ union {
        struct {
            short Q[64][72];   // +8 pad: stride 144B = 9*16B (aligned b128, <=2-way banks)
            short K[64][72];
            short P[64][72];
        } s;
        unsigned short U[64][264];  // epilogue reuse (bf16 unnormalized O)
    } lds;
    __shared__ float Llds[64];

    const int blk = blockIdx.x;
    const int bh = blk >> 4, qt = blk & 15;
    const int t = threadIdx.x;
    const int w = t >> 6, lane = t & 63;
    const int c = lane & 15, hi = lane >> 4;

    const size_t base = (size_t)bh * SEQ * DIM;

    // ---- stage Q tile (central query group rows 2048 + qt*64 ..) as bf16
    {
        const float* qp = query + base + (size_t)(2048 + qt * 64) * DIM;
#pragma unroll
        for (int k2 = 0; k2 < 4; ++k2) {
            int u = t + k2 * 256;
            int row = u >> 4, ci = (u & 15) * 4;
            float4 qv = *(const float4*)(qp + row * 64 + ci);
            bf16x4 h;
            h[0] = f2bf(qv.x); h[1] = f2bf(qv.y); h[2] = f2bf(qv.z); h[3] = f2bf(qv.w);
            *(bf16x4*)&lds.s.Q[row][ci] = h;
        }
    }
    __syncthreads();
    // A-frags of Q for this wave's 16-row S strip (A[m=lane&15][k=quad*8+j])
    bf16x8 aq0 = *(const bf16x8*)&lds.s.Q[w * 16 + c][hi * 8];
    bf16x8 aq1 = *(const bf16x8*)&lds.s.Q[w * 16 + c][32 + hi * 8];

    f32x4 Uacc[4][4];   // [mt][nt]: 64 rows x 64 dims (this wave's value-group)
#pragma unroll
    for (int mt = 0; mt < 4; ++mt)
#pragma unroll
        for (int nt = 0; nt < 4; ++nt)
            Uacc[mt][nt] = (f32x4){0.f, 0.f, 0.f, 0.f};
    float Lacc[4] = {0.f, 0.f, 0.f, 0.f};

    const float* kp = key + base + (size_t)2048 * DIM;            // central key group
    const float* vgrp = value + base + (size_t)w * PQ * DIM;      // group w rows, dims 0..63

    for (int kc = 0; kc < 16; ++kc) {
        // ---- stage K chunk (64 keys) as bf16
        {
            const float* kcp = kp + (size_t)kc * 64 * DIM;
#pragma unroll
            for (int k2 = 0; k2 < 4; ++k2) {
                int u = t + k2 * 256;
                int row = u >> 4, ci = (u & 15) * 4;
                float4 kv = *(const float4*)(kcp + row * 64 + ci);
                bf16x4 h;
                h[0] = f2bf(kv.x); h[1] = f2bf(kv.y); h[2] = f2bf(kv.z); h[3] = f2bf(kv.w);
                *(bf16x4*)&lds.s.K[row][ci] = h;
            }
        }
        __syncthreads();
        // ---- S strip: rows w*16..+15 x 64 keys  (B[k=d][n=key] from K row-major)
        f32x4 sacc[4];
#pragma unroll
        for (int nt = 0; nt < 4; ++nt) sacc[nt] = (f32x4){0.f, 0.f, 0.f, 0.f};
#pragma unroll
        for (int nt = 0; nt < 4; ++nt) {
            bf16x8 bk = *(const bf16x8*)&lds.s.K[nt * 16 + c][hi * 8];
            sacc[nt] = __builtin_amdgcn_mfma_f32_16x16x32_bf16(aq0, bk, sacc[nt], 0, 0, 0);
        }
#pragma unroll
        for (int nt = 0; nt < 4; ++nt) {
            bf16x8 bk = *(const bf16x8*)&lds.s.K[nt * 16 + c][32 + hi * 8];
            sacc[nt] = __builtin_amdgcn_mfma_f32_16x16x32_bf16(aq1, bk, sacc[nt], 0, 0, 0);
        }
        // ---- P = exp(S*scale); L row-sums via shuffle; P -> LDS (bf16, A-layout source)
        float p[4][4];
#pragma unroll
        for (int nt = 0; nt < 4; ++nt)
#pragma unroll
            for (int r = 0; r < 4; ++r)
                p[nt][r] = __expf(sacc[nt][r] * 0.125f);
#pragma unroll
        for (int r = 0; r < 4; ++r) {
            float rs = p[0][r] + p[1][r] + p[2][r] + p[3][r];
            rs += __shfl_xor(rs, 1); rs += __shfl_xor(rs, 2);
            rs += __shfl_xor(rs, 4); rs += __shfl_xor(rs, 8);
            Lacc[r] += rs;
        }
#pragma unroll
        for (int nt = 0; nt < 4; ++nt)
#pragma unroll
            for (int r = 0; r < 4; ++r)
                lds.s.P[w * 16 + hi * 4 + r][nt * 16 + c] = (unsigned short)f2bf(p[nt][r]);
        __syncthreads();
        // ---- U += P @ V_group(w): A-frags of P from LDS, B-frags of V direct from global
        bf16x8 ap[4][2];
#pragma unroll
        for (int mt = 0; mt < 4; ++mt) {
            ap[mt][0] = *(const bf16x8*)&lds.s.P[mt * 16 + c][hi * 8];
            ap[mt][1] = *(const bf16x8*)&lds.s.P[mt * 16 + c][32 + hi * 8];
        }
        const float* vp = vgrp + (size_t)kc * 64 * DIM;
#pragma unroll
        for (int kt = 0; kt < 2; ++kt) {
#pragma unroll
            for (int nt = 0; nt < 4; ++nt) {
                const float* vpp = vp + (kt * 32 + hi * 8) * 64 + nt * 16 + c;
                bf16x8 bv;
#pragma unroll
                for (int j = 0; j < 8; ++j) bv[j] = f2bf(vpp[j * 64]);
#pragma unroll
                for (int mt = 0; mt < 4; ++mt)
                    Uacc[mt][nt] = __builtin_amdgcn_mfma_f32_16x16x32_bf16(ap[mt][kt], bv, Uacc[mt][nt], 0, 0, 0);
            }
        }
        __syncthreads();   // protect K/P for next chunk's staging
    }

    // ---- epilogue: dump U (bf16) and L to LDS, then combine
#pragma unroll
    for (int mt = 0; mt < 4; ++mt)
#pragma unroll
        for (int nt = 0; nt < 4; ++nt)
#pragma unroll
            for (int r = 0; r < 4; ++r)
                lds.U[mt * 16 + hi * 4 + r][w * 64 + nt * 16 + c] =
                    (unsigned short)f2bf(Uacc[mt][nt][r]);
    if (c == 0) {
#pragma unroll
        for (int r = 0; r < 4; ++r) Llds[w * 16 + hi * 4 + r] = Lacc[r];
    }
    __syncthreads();

    const float* nsq = ws + bh * 16;
    const float* vsw = ws + 512 + bh * 256;
    const int dd = t & 63, rq = t >> 6;
    float sg[4][4], ssum[4], omp[4], ov[4];
    const float inv22 = 1.0f / nsq[10];   // nsq[c0=2][c1=2]
#pragma unroll
    for (int gi = 0; gi < 4; ++gi) {
        float ss = 0.f, os = 0.f, ovv = 0.f;
#pragma unroll
        for (int gj = 0; gj < 4; ++gj) {
            float sgv = sqrtf(nsq[gi * 4 + gj] * inv22);
            sg[gi][gj] = sgv;
            ss += sgv;
            float om = fmaxf(1.0f - sgv, 0.0f);
            os += om;
            ovv += om * vsw[gj * 64 + dd];
        }
        ssum[gi] = ss; omp[gi] = os * 1024.0f; ov[gi] = ovv;
    }
    float* attn_out = out + base;
    float* lse_out = out + (size_t)BH_TOT * SEQ * DIM + (size_t)bh * SEQ;
    for (int k = 0; k < 16; ++k) {
        const int r = k * 4 + rq;
        const float u0 = bf2f(lds.U[r][dd]);
        const float u1 = bf2f(lds.U[r][64 + dd]);
        const float u2 = bf2f(lds.U[r][128 + dd]);
        const float u3 = bf2f(lds.U[r][192 + dd]);
        const float Lr = Llds[r];
        const int orow = qt * 64 + r;
#pragma unroll
        for (int gi = 0; gi < 4; ++gi) {
            float num = ov[gi] + sg[gi][0] * u0 + sg[gi][1] * u1 + sg[gi][2] * u2 + sg[gi][3] * u3;
            float den = omp[gi] + ssum[gi] * Lr;
            attn_out[(size_t)(gi * 1024 + orow) * 64 + dd] = num / den;
            if (dd == gi) lse_out[gi * 1024 + orow] = __logf(den);
        }
    }
}

extern "C" void kernel_launch(void* const* d_in, const int* in_sizes, int n_in,
                              void* d_out, int out_size, void* d_ws, size_t ws_size,
                              hipStream_t stream)
{
    (void)in_sizes; (void)n_in; (void)out_size; (void)ws_size;
    const float* query = (const float*)d_in[0];
    const float* key   = (const float*)d_in[1];
    const float* value = (const float*)d_in[2];
    float* ws   = (float*)d_ws;
    float* outp = (float*)d_out;
    prep_kernel<<<256, 256, 0, stream>>>(query, key, value, ws);
    kattn_kernel<<<512, 256, 0, stream>>>(query, key, value, ws, outp);
}

// Round 3
// 244.850 us; speedup vs baseline: 1.0179x; 1.0179x over previous
//
#include <hip/hip_runtime.h>
#include <hip/hip_bf16.h>

// KroneckerAttention on MI355X.
// B=2,H=16 (BH=32), NQ=NK=4096, D=64, m=n=4, pq=pk=1024, c0=c1=2, scale=1/8.
//
// ws layout:
//   floats [0,512)    : nsq[bh][gi][gj]
//   floats [512,8704) : vsum[bh][gj][dd]
//   bytes  [34816, +4MB)  : Qb  bf16 A-frags, pre-scaled by 0.125*log2(e)
//   bytes  [+4MB, +8MB)   : Kb  bf16 B-frags (central key group)
//   bytes  [+8MB, +24MB)  : Vb  bf16 B-frags (all value rows)
// Fast path requires ws_size >= 25200640 bytes; else fall back to the
// self-contained R2 kernel (kattn_fallback).

#define BH_TOT 32
#define SEQ    4096
#define DIM    64
#define PQ     1024

#define QB_OFF 34816u
#define KB_OFF (QB_OFF + 4u*1024u*1024u)
#define VB_OFF (KB_OFF + 4u*1024u*1024u)
#define WS_NEED (VB_OFF + 16u*1024u*1024u)

#define QSCALE 0.1803368801111204f   // 0.125 * log2(e)

typedef __attribute__((ext_vector_type(8))) short bf16x8;
typedef __attribute__((ext_vector_type(4))) short bf16x4;
typedef __attribute__((ext_vector_type(4))) float f32x4;

__device__ __forceinline__ short f2bf(float x) {
    unsigned u = __float_as_uint(x);
    u = u + 0x7fffu + ((u >> 16) & 1u);   // RNE truncate to bf16
    return (short)(u >> 16);
}
__device__ __forceinline__ float bf2f(unsigned short h) {
    return __uint_as_float(((unsigned)h) << 16);
}

// ---------------- prep_norm: 128 blocks (bh,gi) -> nsq ---------------------
__global__ __launch_bounds__(256) void prep_norm(
    const float* __restrict__ query, const float* __restrict__ key,
    float* __restrict__ ws)
{
    __shared__ float ksm[4][64];
    __shared__ float wsum[4][4];
    const int t = threadIdx.x;
    const int bh = blockIdx.x >> 2, gi = blockIdx.x & 3;
    ksm[t >> 6][t & 63] = key[((size_t)bh * SEQ + (size_t)(t >> 6) * PQ) * DIM + (t & 63)];
    __syncthreads();
    const int c4 = t & 15;
    float k0[4], k1[4], k2[4], k3[4];
#pragma unroll
    for (int g = 0; g < 4; ++g) {
        k0[g] = ksm[g][c4 * 4 + 0]; k1[g] = ksm[g][c4 * 4 + 1];
        k2[g] = ksm[g][c4 * 4 + 2]; k3[g] = ksm[g][c4 * 4 + 3];
    }
    float acc[4] = {0.f, 0.f, 0.f, 0.f};
    const float4* qv = (const float4*)(query + ((size_t)bh * SEQ + (size_t)gi * PQ) * DIM);
    for (int it = 0; it < 64; ++it) {
        const int r = it * 16 + (t >> 4);
        float4 q = qv[r * 16 + c4];
#pragma unroll
        for (int g = 0; g < 4; ++g) {
            float p = q.x * k0[g] + q.y * k1[g] + q.z * k2[g] + q.w * k3[g];
            p += __shfl_xor(p, 1); p += __shfl_xor(p, 2);
            p += __shfl_xor(p, 4); p += __shfl_xor(p, 8);
            acc[g] += p * p;          // each row counted 16x; /16 at the end
        }
    }
#pragma unroll
    for (int g = 0; g < 4; ++g) {
        acc[g] += __shfl_xor(acc[g], 16);
        acc[g] += __shfl_xor(acc[g], 32);
    }
    if ((t & 63) == 0) {
#pragma unroll
        for (int g = 0; g < 4; ++g) wsum[t >> 6][g] = acc[g];
    }
    __syncthreads();
    if (t < 4) {
        float s = (wsum[0][t] + wsum[1][t] + wsum[2][t] + wsum[3][t]) * (1.0f / 16.0f);
        ws[bh * 16 + gi * 4 + t] = s;
    }
}

// ---------------- prep_vsum: 128 blocks (bh,gj) -> vsum --------------------
__global__ __launch_bounds__(256) void prep_vsum(
    const float* __restrict__ value, float* __restrict__ ws)
{
    __shared__ float part[16][16][4];
    const int t = threadIdx.x;
    const int bh = blockIdx.x >> 2, gj = blockIdx.x & 3;
    const float4* vv = (const float4*)(value + ((size_t)bh * SEQ + (size_t)gj * PQ) * DIM);
    const int c4 = t & 15, rg = t >> 4;
    float a0 = 0.f, a1 = 0.f, a2 = 0.f, a3 = 0.f;
    for (int r = rg; r < 1024; r += 16) {
        float4 x = vv[r * 16 + c4];
        a0 += x.x; a1 += x.y; a2 += x.z; a3 += x.w;
    }
    part[rg][c4][0] = a0; part[rg][c4][1] = a1;
    part[rg][c4][2] = a2; part[rg][c4][3] = a3;
    __syncthreads();
    if (t < 64) {
        const int cc = t >> 2, comp = t & 3;
        float s = 0.f;
#pragma unroll
        for (int g = 0; g < 16; ++g) s += part[g][cc][comp];
        ws[512 + bh * 256 + gj * 64 + cc * 4 + comp] = s;
    }
}

// ---------------- conv_q: 512 blocks (bh,qt) -> Qb A-frags (pre-scaled) ----
__global__ __launch_bounds__(256) void conv_q(
    const float* __restrict__ query, char* __restrict__ wsb)
{
    const int t = threadIdx.x;
    const int bh = blockIdx.x >> 4, qt = blockIdx.x & 15;
#pragma unroll
    for (int i = 0; i < 2; ++i) {
        const int sid = t + i * 256;
        const int mt = sid >> 7, kh = (sid >> 6) & 1, lane = sid & 63;
        const int c = lane & 15, hi = lane >> 4;
        const float* p = query + ((size_t)bh * SEQ + 2048 + qt * 64 + mt * 16 + c) * DIM
                         + kh * 32 + hi * 8;
        float4 a = *(const float4*)p, b = *(const float4*)(p + 4);
        bf16x8 h;
        h[0] = f2bf(a.x * QSCALE); h[1] = f2bf(a.y * QSCALE);
        h[2] = f2bf(a.z * QSCALE); h[3] = f2bf(a.w * QSCALE);
        h[4] = f2bf(b.x * QSCALE); h[5] = f2bf(b.y * QSCALE);
        h[6] = f2bf(b.z * QSCALE); h[7] = f2bf(b.w * QSCALE);
        const size_t fidx = ((size_t)(bh * 16 + qt) * 4 + mt) * 2 + kh;
        *(bf16x8*)(wsb + QB_OFF + fidx * 1024 + lane * 16) = h;
    }
}

// ---------------- conv_k: 512 blocks (bh,kc) -> Kb B-frags -----------------
__global__ __launch_bounds__(256) void conv_k(
    const float* __restrict__ key, char* __restrict__ wsb)
{
    const int t = threadIdx.x;
    const int bh = blockIdx.x >> 4, kc = blockIdx.x & 15;
#pragma unroll
    for (int i = 0; i < 2; ++i) {
        const int sid = t + i * 256;
        const int kh = sid >> 8, nt = (sid >> 6) & 3, lane = sid & 63;
        const int c = lane & 15, hi = lane >> 4;
        const float* p = key + ((size_t)bh * SEQ + 2048 + kc * 64 + nt * 16 + c) * DIM
                         + kh * 32 + hi * 8;
        float4 a = *(const float4*)p, b = *(const float4*)(p + 4);
        bf16x8 h;
        h[0] = f2bf(a.x); h[1] = f2bf(a.y); h[2] = f2bf(a.z); h[3] = f2bf(a.w);
        h[4] = f2bf(b.x); h[5] = f2bf(b.y); h[6] = f2bf(b.z); h[7] = f2bf(b.w);
        const size_t fidx = ((size_t)(bh * 16 + kc) * 2 + kh) * 4 + nt;
        *(bf16x8*)(wsb + KB_OFF + fidx * 1024 + lane * 16) = h;
    }
}

// ---------------- conv_v: 2048 blocks (bh,gj,kc) -> Vb B-frags -------------
__global__ __launch_bounds__(256) void conv_v(
    const float* __restrict__ value, char* __restrict__ wsb)
{
    __shared__ float Ls[64][68];
    const int t = threadIdx.x;
    const int blk = blockIdx.x;
    const int bh = blk >> 6, gj = (blk >> 4) & 3, kc = blk & 15;
    const float* src = value + ((size_t)bh * SEQ + gj * PQ + kc * 64) * DIM;
#pragma unroll
    for (int i = 0; i < 4; ++i) {
        const int u = t + i * 256;
        const int row = u >> 4, c4 = (u & 15) * 4;
        *(float4*)&Ls[row][c4] = *(const float4*)(src + row * 64 + c4);
    }
    __syncthreads();
#pragma unroll
    for (int i = 0; i < 2; ++i) {
        const int sid = t + i * 256;
        const int kt = sid >> 8, nt = (sid >> 6) & 3, lane = sid & 63;
        const int c = lane & 15, hi = lane >> 4;
        bf16x8 h;
#pragma unroll
        for (int j = 0; j < 8; ++j) h[j] = f2bf(Ls[kt * 32 + hi * 8 + j][nt * 16 + c]);
        const size_t fidx = (((size_t)(bh * 4 + gj) * 16 + kc) * 2 + kt) * 4 + nt;
        *(bf16x8*)(wsb + VB_OFF + fidx * 1024 + lane * 16) = h;
    }
}

// ---------------- kattn2: fragment-fed attention + combine -----------------
// grid = 512 (bh*16 + qt), block = 256 (4 waves). Wave w owns value-group w.
__global__ __launch_bounds__(256, 2) void kattn2(
    const char* __restrict__ wsb, float* __restrict__ out)
{
    __shared__ union {
        short P[2][64][72];     // double-buffered P (bf16), +8 pad
        float Uf[64][260];      // epilogue: fp32 unnormalized O (4 groups x 64)
    } lds;
    __shared__ float Llds[64];

    const int blk = blockIdx.x;
    const int bh = blk >> 4, qt = blk & 15;
    const int t = threadIdx.x;
    const int w = t >> 6, lane = t & 63;
    const int c = lane & 15, hi = lane >> 4;

    // Q A-frags for this wave's 16-row strip (pre-scaled by 0.125*log2e)
    const char* qb = wsb + QB_OFF + (((size_t)(bh * 16 + qt) * 4 + w) * 2) * 1024 + lane * 16;
    const bf16x8 aq0 = *(const bf16x8*)qb;
    const bf16x8 aq1 = *(const bf16x8*)(qb + 1024);

    const char* kb = wsb + KB_OFF + ((size_t)(bh * 16) * 2 * 4) * 1024 + lane * 16;
    const char* vb = wsb + VB_OFF + (((size_t)(bh * 4 + w) * 16) * 2 * 4) * 1024 + lane * 16;

    f32x4 Uacc[4][4];   // [mt][nt]: 64 rows x 64 dims of this wave's group
#pragma unroll
    for (int mt = 0; mt < 4; ++mt)
#pragma unroll
        for (int nt = 0; nt < 4; ++nt)
            Uacc[mt][nt] = (f32x4){0.f, 0.f, 0.f, 0.f};
    float Lacc[4] = {0.f, 0.f, 0.f, 0.f};

    for (int kc = 0; kc < 16; ++kc) {
        const int buf = kc & 1;
        // ---- K B-frags (shared across waves; L1 hits) + QK^T
        const char* kcb = kb + (size_t)kc * 8 * 1024;
        f32x4 sacc[4];
#pragma unroll
        for (int nt = 0; nt < 4; ++nt) sacc[nt] = (f32x4){0.f, 0.f, 0.f, 0.f};
#pragma unroll
        for (int nt = 0; nt < 4; ++nt) {
            bf16x8 bk = *(const bf16x8*)(kcb + nt * 1024);
            sacc[nt] = __builtin_amdgcn_mfma_f32_16x16x32_bf16(aq0, bk, sacc[nt], 0, 0, 0);
        }
#pragma unroll
        for (int nt = 0; nt < 4; ++nt) {
            bf16x8 bk = *(const bf16x8*)(kcb + (4 + nt) * 1024);
            sacc[nt] = __builtin_amdgcn_mfma_f32_16x16x32_bf16(aq1, bk, sacc[nt], 0, 0, 0);
        }
        // ---- P = 2^S (scale folded into Q); L row-sums; P -> LDS
        float p[4][4];
#pragma unroll
        for (int nt = 0; nt < 4; ++nt)
#pragma unroll
            for (int r = 0; r < 4; ++r)
                p[nt][r] = __builtin_amdgcn_exp2f(sacc[nt][r]);
#pragma unroll
        for (int r = 0; r < 4; ++r) {
            float rs = p[0][r] + p[1][r] + p[2][r] + p[3][r];
            rs += __shfl_xor(rs, 1); rs += __shfl_xor(rs, 2);
            rs += __shfl_xor(rs, 4); rs += __shfl_xor(rs, 8);
            Lacc[r] += rs;
        }
#pragma unroll
        for (int nt = 0; nt < 4; ++nt)
#pragma unroll
            for (int r = 0; r < 4; ++r)
                lds.P[buf][w * 16 + hi * 4 + r][nt * 16 + c] = f2bf(p[nt][r]);
        __syncthreads();
        // ---- U += P @ V_group(w): A-frags of all 64 rows, V B-frags direct
        bf16x8 ap[4][2];
#pragma unroll
        for (int mt = 0; mt < 4; ++mt) {
            ap[mt][0] = *(const bf16x8*)&lds.P[buf][mt * 16 + c][hi * 8];
            ap[mt][1] = *(const bf16x8*)&lds.P[buf][mt * 16 + c][32 + hi * 8];
        }
        const char* vcb = vb + (size_t)kc * 8 * 1024;
#pragma unroll
        for (int kt = 0; kt < 2; ++kt) {
#pragma unroll
            for (int nt = 0; nt < 4; ++nt) {
                bf16x8 bv = *(const bf16x8*)(vcb + (kt * 4 + nt) * 1024);
#pragma unroll
                for (int mt = 0; mt < 4; ++mt)
                    Uacc[mt][nt] = __builtin_amdgcn_mfma_f32_16x16x32_bf16(ap[mt][kt], bv, Uacc[mt][nt], 0, 0, 0);
            }
        }
        // no trailing barrier: P is double-buffered (write of buf X in iter
        // k+2 is separated from reads of buf X in iter k by barrier k+1)
    }

    __syncthreads();   // all P reads done; reuse LDS as fp32 U
#pragma unroll
    for (int mt = 0; mt < 4; ++mt)
#pragma unroll
        for (int nt = 0; nt < 4; ++nt)
#pragma unroll
            for (int r = 0; r < 4; ++r)
                lds.Uf[mt * 16 + hi * 4 + r][w * 64 + nt * 16 + c] = Uacc[mt][nt][r];
    if (c == 0) {
#pragma unroll
        for (int r = 0; r < 4; ++r) Llds[w * 16 + hi * 4 + r] = Lacc[r];
    }
    __syncthreads();

    const float* nsq = (const float*)wsb + (size_t)bh * 16;
    const float* vsw = (const float*)wsb + 512 + (size_t)bh * 256;
    const int dd = t & 63, rq = t >> 6;
    float sg[4][4], ssum[4], omp[4], ov[4];
    const float inv22 = 1.0f / nsq[10];   // nsq[c0=2][c1=2]
#pragma unroll
    for (int gi = 0; gi < 4; ++gi) {
        float ss = 0.f, os = 0.f, ovv = 0.f;
#pragma unroll
        for (int gj = 0; gj < 4; ++gj) {
            float sgv = sqrtf(nsq[gi * 4 + gj] * inv22);
            sg[gi][gj] = sgv;
            ss += sgv;
            float om = fmaxf(1.0f - sgv, 0.0f);
            os += om;
            ovv += om * vsw[gj * 64 + dd];
        }
        ssum[gi] = ss; omp[gi] = os * 1024.0f; ov[gi] = ovv;
    }
    const size_t base = (size_t)bh * SEQ * DIM;
    float* attn_out = out + base;
    float* lse_out = out + (size_t)BH_TOT * SEQ * DIM + (size_t)bh * SEQ;
    for (int k = 0; k < 16; ++k) {
        const int r = k * 4 + rq;
        const float u0 = lds.Uf[r][dd];
        const float u1 = lds.Uf[r][64 + dd];
        const float u2 = lds.Uf[r][128 + dd];
        const float u3 = lds.Uf[r][192 + dd];
        const float Lr = Llds[r];
        const int orow = qt * 64 + r;
#pragma unroll
        for (int gi = 0; gi < 4; ++gi) {
            float num = ov[gi] + sg[gi][0] * u0 + sg[gi][1] * u1 + sg[gi][2] * u2 + sg[gi][3] * u3;
            float den = omp[gi] + ssum[gi] * Lr;
            attn_out[(size_t)(gi * 1024 + orow) * 64 + dd] = num / den;
            if (dd == gi) lse_out[gi * 1024 + orow] = __logf(den);
        }
    }
}

// ---------------- fallback (R2 kernel, used when ws is too small) ----------
__global__ __launch_bounds__(256, 2) void kattn_fallback(
    const float* __restrict__ query, const float* __restrict__ key,
    const float* __restrict__ value, const float* __restrict__ ws,
    float* __restrict__ out)
{
    __shared__ union {
        struct {
            short Q[64][72];
            short K[64][72];
            short P[64][72];
        } s;
        unsigned short U[64][264];
    } lds;
    __shared__ float Llds[64];

    const int blk = blockIdx.x;
    const int bh = blk >> 4, qt = blk & 15;
    const int t = threadIdx.x;
    const int w = t >> 6, lane = t & 63;
    const int c = lane & 15, hi = lane >> 4;

    const size_t base = (size_t)bh * SEQ * DIM;

    {
        const float* qp = query + base + (size_t)(2048 + qt * 64) * DIM;
#pragma unroll
        for (int k2 = 0; k2 < 4; ++k2) {
            int u = t + k2 * 256;
            int row = u >> 4, ci = (u & 15) * 4;
            float4 qv = *(const float4*)(qp + row * 64 + ci);
            bf16x4 h;
            h[0] = f2bf(qv.x); h[1] = f2bf(qv.y); h[2] = f2bf(qv.z); h[3] = f2bf(qv.w);
            *(bf16x4*)&lds.s.Q[row][ci] = h;
        }
    }
    __syncthreads();
    bf16x8 aq0 = *(const bf16x8*)&lds.s.Q[w * 16 + c][hi * 8];
    bf16x8 aq1 = *(const bf16x8*)&lds.s.Q[w * 16 + c][32 + hi * 8];

    f32x4 Uacc[4][4];
#pragma unroll
    for (int mt = 0; mt < 4; ++mt)
#pragma unroll
        for (int nt = 0; nt < 4; ++nt)
            Uacc[mt][nt] = (f32x4){0.f, 0.f, 0.f, 0.f};
    float Lacc[4] = {0.f, 0.f, 0.f, 0.f};

    const float* kp = key + base + (size_t)2048 * DIM;
    const float* vgrp = value + base + (size_t)w * PQ * DIM;

    for (int kc = 0; kc < 16; ++kc) {
        {
            const float* kcp = kp + (size_t)kc * 64 * DIM;
#pragma unroll
            for (int k2 = 0; k2 < 4; ++k2) {
                int u = t + k2 * 256;
                int row = u >> 4, ci = (u & 15) * 4;
                float4 kv = *(const float4*)(kcp + row * 64 + ci);
                bf16x4 h;
                h[0] = f2bf(kv.x); h[1] = f2bf(kv.y); h[2] = f2bf(kv.z); h[3] = f2bf(kv.w);
                *(bf16x4*)&lds.s.K[row][ci] = h;
            }
        }
        __syncthreads();
        f32x4 sacc[4];
#pragma unroll
        for (int nt = 0; nt < 4; ++nt) sacc[nt] = (f32x4){0.f, 0.f, 0.f, 0.f};
#pragma unroll
        for (int nt = 0; nt < 4; ++nt) {
            bf16x8 bk = *(const bf16x8*)&lds.s.K[nt * 16 + c][hi * 8];
            sacc[nt] = __builtin_amdgcn_mfma_f32_16x16x32_bf16(aq0, bk, sacc[nt], 0, 0, 0);
        }
#pragma unroll
        for (int nt = 0; nt < 4; ++nt) {
            bf16x8 bk = *(const bf16x8*)&lds.s.K[nt * 16 + c][32 + hi * 8];
            sacc[nt] = __builtin_amdgcn_mfma_f32_16x16x32_bf16(aq1, bk, sacc[nt], 0, 0, 0);
        }
        float p[4][4];
#pragma unroll
        for (int nt = 0; nt < 4; ++nt)
#pragma unroll
            for (int r = 0; r < 4; ++r)
                p[nt][r] = __expf(sacc[nt][r] * 0.125f);
#pragma unroll
        for (int r = 0; r < 4; ++r) {
            float rs = p[0][r] + p[1][r] + p[2][r] + p[3][r];
            rs += __shfl_xor(rs, 1); rs += __shfl_xor(rs, 2);
            rs += __shfl_xor(rs, 4); rs += __shfl_xor(rs, 8);
            Lacc[r] += rs;
        }
#pragma unroll
        for (int nt = 0; nt < 4; ++nt)
#pragma unroll
            for (int r = 0; r < 4; ++r)
                lds.s.P[w * 16 + hi * 4 + r][nt * 16 + c] = (unsigned short)f2bf(p[nt][r]);
        __syncthreads();
        bf16x8 ap[4][2];
#pragma unroll
        for (int mt = 0; mt < 4; ++mt) {
            ap[mt][0] = *(const bf16x8*)&lds.s.P[mt * 16 + c][hi * 8];
            ap[mt][1] = *(const bf16x8*)&lds.s.P[mt * 16 + c][32 + hi * 8];
        }
        const float* vp = vgrp + (size_t)kc * 64 * DIM;
#pragma unroll
        for (int kt = 0; kt < 2; ++kt) {
#pragma unroll
            for (int nt = 0; nt < 4; ++nt) {
                const float* vpp = vp + (kt * 32 + hi * 8) * 64 + nt * 16 + c;
                bf16x8 bv;
#pragma unroll
                for (int j = 0; j < 8; ++j) bv[j] = f2bf(vpp[j * 64]);
#pragma unroll
                for (int mt = 0; mt < 4; ++mt)
                    Uacc[mt][nt] = __builtin_amdgcn_mfma_f32_16x16x32_bf16(ap[mt][kt], bv, Uacc[mt][nt], 0, 0, 0);
            }
        }
        __syncthreads();
    }

#pragma unroll
    for (int mt = 0; mt < 4; ++mt)
#pragma unroll
        for (int nt = 0; nt < 4; ++nt)
#pragma unroll
            for (int r = 0; r < 4; ++r)
                lds.U[mt * 16 + hi * 4 + r][w * 64 + nt * 16 + c] =
                    (unsigned short)f2bf(Uacc[mt][nt][r]);
    if (c == 0) {
#pragma unroll
        for (int r = 0; r < 4; ++r) Llds[w * 16 + hi * 4 + r] = Lacc[r];
    }
    __syncthreads();

    const float* nsq = ws + bh * 16;
    const float* vsw = ws + 512 + bh * 256;
    const int dd = t & 63, rq = t >> 6;
    float sg[4][4], ssum[4], omp[4], ov[4];
    const float inv22 = 1.0f / nsq[10];
#pragma unroll
    for (int gi = 0; gi < 4; ++gi) {
        float ss = 0.f, os = 0.f, ovv = 0.f;
#pragma unroll
        for (int gj = 0; gj < 4; ++gj) {
            float sgv = sqrtf(nsq[gi * 4 + gj] * inv22);
            sg[gi][gj] = sgv;
            ss += sgv;
            float om = fmaxf(1.0f - sgv, 0.0f);
            os += om;
            ovv += om * vsw[gj * 64 + dd];
        }
        ssum[gi] = ss; omp[gi] = os * 1024.0f; ov[gi] = ovv;
    }
    float* attn_out = out + base;
    float* lse_out = out + (size_t)BH_TOT * SEQ * DIM + (size_t)bh * SEQ;
    for (int k = 0; k < 16; ++k) {
        const int r = k * 4 + rq;
        const float u0 = bf2f(lds.U[r][dd]);
        const float u1 = bf2f(lds.U[r][64 + dd]);
        const float u2 = bf2f(lds.U[r][128 + dd]);
        const float u3 = bf2f(lds.U[r][192 + dd]);
        const float Lr = Llds[r];
        const int orow = qt * 64 + r;
#pragma unroll
        for (int gi = 0; gi < 4; ++gi) {
            float num = ov[gi] + sg[gi][0] * u0 + sg[gi][1] * u1 + sg[gi][2] * u2 + sg[gi][3] * u3;
            float den = omp[gi] + ssum[gi] * Lr;
            attn_out[(size_t)(gi * 1024 + orow) * 64 + dd] = num / den;
            if (dd == gi) lse_out[gi * 1024 + orow] = __logf(den);
        }
    }
}

extern "C" void kernel_launch(void* const* d_in, const int* in_sizes, int n_in,
                              void* d_out, int out_size, void* d_ws, size_t ws_size,
                              hipStream_t stream)
{
    (void)in_sizes; (void)n_in; (void)out_size;
    const float* query = (const float*)d_in[0];
    const float* key   = (const float*)d_in[1];
    const float* value = (const float*)d_in[2];
    float* ws   = (float*)d_ws;
    char*  wsb  = (char*)d_ws;
    float* outp = (float*)d_out;

    prep_norm<<<128, 256, 0, stream>>>(query, key, ws);
    prep_vsum<<<128, 256, 0, stream>>>(value, ws);
    if (ws_size >= WS_NEED) {
        conv_q<<<512, 256, 0, stream>>>(query, wsb);
        conv_k<<<512, 256, 0, stream>>>(key, wsb);
        conv_v<<<2048, 256, 0, stream>>>(value, wsb);
        kattn2<<<512, 256, 0, stream>>>(wsb, outp);
    } else {
        kattn_fallback<<<512, 256, 0, stream>>>(query, key, value, ws, outp);
    }
}

// Round 4
// 185.391 us; speedup vs baseline: 1.3444x; 1.3207x over previous
//
#include <hip/hip_runtime.h>
#include <hip/hip_bf16.h>

// KroneckerAttention on MI355X.
// B=2,H=16 (BH=32), NQ=NK=4096, D=64, m=n=4, pq=pk=1024, c0=c1=2, scale=1/8.
//
// ws layout:
//   floats [0,512)    : nsq[bh][gi][gj]
//   floats [512,8704) : vsum[bh][gj][dd]   (atomically accumulated by conv_v)
//   bytes  [34816, +4MB)  : Qb  bf16 16x16x32 B-frags, pre-scaled 0.125*log2e
//   bytes  [+4MB, +8MB)   : Kb  bf16 16x16x32 A-frags (central key group)
//   bytes  [+8MB, +24MB)  : Vb  f16  16x16x16 B-frags (all value rows)

#define BH_TOT 32
#define SEQ    4096
#define DIM    64
#define PQ     1024

#define QB_OFF 34816u
#define KB_OFF (QB_OFF + 4u*1024u*1024u)
#define VB_OFF (KB_OFF + 4u*1024u*1024u)
#define WS_NEED (VB_OFF + 16u*1024u*1024u)
#define WS_NEED_FB 34816u

#define QSCALE 0.1803368801111204f   // 0.125 * log2(e)

typedef __attribute__((ext_vector_type(8))) short bf16x8;
typedef __attribute__((ext_vector_type(4))) short bf16x4;
typedef __attribute__((ext_vector_type(4))) float f32x4;
typedef __attribute__((ext_vector_type(4))) _Float16 f16x4;
typedef __attribute__((ext_vector_type(8))) _Float16 f16x8;

__device__ __forceinline__ short f2bf(float x) {
    unsigned u = __float_as_uint(x);
    u = u + 0x7fffu + ((u >> 16) & 1u);   // RNE truncate to bf16
    return (short)(u >> 16);
}
__device__ __forceinline__ float bf2f(unsigned short h) {
    return __uint_as_float(((unsigned)h) << 16);
}

// ---------------- prep_norm2: 128 blocks (bh,gi) -> nsq via MFMA -----------
// Also zero-inits vsum (conv_v accumulates into it later in stream order).
__global__ __launch_bounds__(256) void prep_norm2(
    const float* __restrict__ query, const float* __restrict__ key,
    float* __restrict__ ws)
{
    __shared__ float ksm[4][64];
    __shared__ float wsum[4][16];
    const int t = threadIdx.x;
    const int bh = blockIdx.x >> 2, gi = blockIdx.x & 3;
    if (t < 64) ws[512 + blockIdx.x * 64 + t] = 0.f;   // 128*64 = 8192 = vsum
    ksm[t >> 6][t & 63] = key[((size_t)bh * SEQ + (size_t)(t >> 6) * PQ) * DIM + (t & 63)];
    __syncthreads();
    const int wv = t >> 6, lane = t & 63, c = lane & 15, hi = lane >> 4;
    bf16x8 bb0, bb1;
#pragma unroll
    for (int j = 0; j < 8; ++j) {
        bb0[j] = (c < 4) ? f2bf(ksm[c][hi * 8 + j]) : (short)0;
        bb1[j] = (c < 4) ? f2bf(ksm[c][32 + hi * 8 + j]) : (short)0;
    }
    float acc0 = 0.f, acc1 = 0.f, acc2 = 0.f, acc3 = 0.f;
    const float* qbase = query + ((size_t)bh * SEQ + (size_t)gi * PQ) * DIM;
    for (int it = 0; it < 16; ++it) {
        const int row = (wv * 16 + it) * 16 + c;
        const float* qp = qbase + (size_t)row * 64 + hi * 8;
        float4 a0 = *(const float4*)qp;
        float4 a1 = *(const float4*)(qp + 4);
        float4 a2 = *(const float4*)(qp + 32);
        float4 a3 = *(const float4*)(qp + 36);
        bf16x8 qa0, qa1;
        qa0[0] = f2bf(a0.x); qa0[1] = f2bf(a0.y); qa0[2] = f2bf(a0.z); qa0[3] = f2bf(a0.w);
        qa0[4] = f2bf(a1.x); qa0[5] = f2bf(a1.y); qa0[6] = f2bf(a1.z); qa0[7] = f2bf(a1.w);
        qa1[0] = f2bf(a2.x); qa1[1] = f2bf(a2.y); qa1[2] = f2bf(a2.z); qa1[3] = f2bf(a2.w);
        qa1[4] = f2bf(a3.x); qa1[5] = f2bf(a3.y); qa1[6] = f2bf(a3.z); qa1[7] = f2bf(a3.w);
        f32x4 s = (f32x4){0.f, 0.f, 0.f, 0.f};
        s = __builtin_amdgcn_mfma_f32_16x16x32_bf16(qa0, bb0, s, 0, 0, 0);
        s = __builtin_amdgcn_mfma_f32_16x16x32_bf16(qa1, bb1, s, 0, 0, 0);
        acc0 += s[0] * s[0]; acc1 += s[1] * s[1];
        acc2 += s[2] * s[2]; acc3 += s[3] * s[3];
    }
    float asum = acc0 + acc1 + acc2 + acc3;
    asum += __shfl_xor(asum, 16);
    asum += __shfl_xor(asum, 32);
    if (lane < 16) wsum[wv][lane] = asum;
    __syncthreads();
    if (t < 4) ws[bh * 16 + gi * 4 + t] = wsum[0][t] + wsum[1][t] + wsum[2][t] + wsum[3][t];
}

// ---------------- conv_qk: blocks [0,512) Q-frags, [512,1024) K-frags ------
__global__ __launch_bounds__(256) void conv_qk(
    const float* __restrict__ query, const float* __restrict__ key,
    char* __restrict__ wsb)
{
    const int t = threadIdx.x;
    if (blockIdx.x < 512) {
        const int bh = blockIdx.x >> 4, qt = blockIdx.x & 15;
#pragma unroll
        for (int i = 0; i < 2; ++i) {
            const int sid = t + i * 256;
            const int mt = sid >> 7, kh = (sid >> 6) & 1, lane = sid & 63;
            const int c = lane & 15, hi = lane >> 4;
            const float* p = query + ((size_t)bh * SEQ + 2048 + qt * 64 + mt * 16 + c) * DIM
                             + kh * 32 + hi * 8;
            float4 a = *(const float4*)p, b = *(const float4*)(p + 4);
            bf16x8 h;
            h[0] = f2bf(a.x * QSCALE); h[1] = f2bf(a.y * QSCALE);
            h[2] = f2bf(a.z * QSCALE); h[3] = f2bf(a.w * QSCALE);
            h[4] = f2bf(b.x * QSCALE); h[5] = f2bf(b.y * QSCALE);
            h[6] = f2bf(b.z * QSCALE); h[7] = f2bf(b.w * QSCALE);
            const size_t fidx = ((size_t)(bh * 16 + qt) * 4 + mt) * 2 + kh;
            *(bf16x8*)(wsb + QB_OFF + fidx * 1024 + lane * 16) = h;
        }
    } else {
        const int b2 = blockIdx.x - 512;
        const int bh = b2 >> 4, kc = b2 & 15;
#pragma unroll
        for (int i = 0; i < 2; ++i) {
            const int sid = t + i * 256;
            const int kh = sid >> 8, nt = (sid >> 6) & 3, lane = sid & 63;
            const int c = lane & 15, hi = lane >> 4;
            const float* p = key + ((size_t)bh * SEQ + 2048 + kc * 64 + nt * 16 + c) * DIM
                             + kh * 32 + hi * 8;
            float4 a = *(const float4*)p, b = *(const float4*)(p + 4);
            bf16x8 h;
            h[0] = f2bf(a.x); h[1] = f2bf(a.y); h[2] = f2bf(a.z); h[3] = f2bf(a.w);
            h[4] = f2bf(b.x); h[5] = f2bf(b.y); h[6] = f2bf(b.z); h[7] = f2bf(b.w);
            const size_t fidx = ((size_t)(bh * 16 + kc) * 2 + kh) * 4 + nt;
            *(bf16x8*)(wsb + KB_OFF + fidx * 1024 + lane * 16) = h;
        }
    }
}

// ---------------- conv_v: 2048 blocks (bh,gj,kc) -> f16 B-frags + vsum -----
__global__ __launch_bounds__(256) void conv_v(
    const float* __restrict__ value, char* __restrict__ wsb, float* __restrict__ ws)
{
    __shared__ float Ls[64][68];
    __shared__ float ps[4][64];
    const int t = threadIdx.x;
    const int blk = blockIdx.x;
    const int bh = blk >> 6, gj = (blk >> 4) & 3, kc = blk & 15;
    const float* src = value + ((size_t)bh * SEQ + gj * PQ + kc * 64) * DIM;
#pragma unroll
    for (int i = 0; i < 4; ++i) {
        const int u = t + i * 256;
        const int row = u >> 4, c4 = (u & 15) * 4;
        *(float4*)&Ls[row][c4] = *(const float4*)(src + row * 64 + c4);
    }
    __syncthreads();
    // vsum partials
    {
        const int d = t & 63, rg = t >> 6;
        float s = 0.f;
#pragma unroll
        for (int i = 0; i < 16; ++i) s += Ls[rg * 16 + i][d];
        ps[rg][d] = s;
    }
    __syncthreads();
    if (t < 64) {
        float tot = ps[0][t] + ps[1][t] + ps[2][t] + ps[3][t];
        atomicAdd(&ws[512 + bh * 256 + gj * 64 + t], tot);
    }
    // f16 fragment emit: b128 = [frag(ktile 2p, dt) half4 | frag(2p+1, dt) half4]
#pragma unroll
    for (int i = 0; i < 2; ++i) {
        const int sid = t + i * 256;
        const int pl = sid >> 8, dt = (sid >> 6) & 3, lane = sid & 63;
        const int c = lane & 15, hi = lane >> 4;
        f16x8 h;
#pragma unroll
        for (int s2 = 0; s2 < 2; ++s2)
#pragma unroll
            for (int j = 0; j < 4; ++j)
                h[s2 * 4 + j] = (_Float16)Ls[(pl * 2 + s2) * 16 + hi * 4 + j][dt * 16 + c];
        const size_t off = ((((size_t)(bh * 4 + gj) * 32 + kc * 2 + pl) * 4 + dt) * 64 + lane) * 16;
        *(f16x8*)(wsb + VB_OFF + off) = h;
    }
}

// ---------------- kattn3: S^T-layout attention, 32 q rows / block ----------
// grid = 1024 (bh*32 + qt32), block = 256 (4 waves). Wave w = key-tile w of
// each 64-key chunk AND value-group w. P exchanged via LDS (f16, b64 packed).
__global__ __launch_bounds__(256, 4) void kattn3(
    const char* __restrict__ wsb, float* __restrict__ out)
{
    __shared__ union {
        _Float16 P[2][32][72];   // [q][key], stride 72 halves (b64-aligned)
        float Uf[32][257];       // epilogue: fp32 U (4 groups x 64 d)
    } lds;
    __shared__ float Llds[32];

    const int blk = blockIdx.x;
    const int bh = blk >> 5, qt = blk & 31;
    const int t = threadIdx.x;
    const int w = t >> 6, lane = t & 63;
    const int c = lane & 15, hi = lane >> 4;

    // Q B-frags (pre-scaled): strips s = qt*2 + qt2
    bf16x8 aq[2][2];
#pragma unroll
    for (int qt2 = 0; qt2 < 2; ++qt2) {
        const int s = qt * 2 + qt2;
        const size_t fr = ((size_t)(bh * 16 + (s >> 2)) * 4 + (s & 3)) * 2;
        aq[qt2][0] = *(const bf16x8*)(wsb + QB_OFF + fr * 1024 + lane * 16);
        aq[qt2][1] = *(const bf16x8*)(wsb + QB_OFF + (fr + 1) * 1024 + lane * 16);
    }
    const char* kb = wsb + KB_OFF + ((size_t)(bh * 16) * 8) * 1024 + (size_t)w * 1024 + lane * 16;
    const char* vb = wsb + VB_OFF + ((size_t)(bh * 4 + w) * 128) * 1024 + lane * 16;

    f32x4 Uacc[2][4];    // [mt][dt]: 32 q x 64 d (this wave's value-group)
#pragma unroll
    for (int mt = 0; mt < 2; ++mt)
#pragma unroll
        for (int dt = 0; dt < 4; ++dt)
            Uacc[mt][dt] = (f32x4){0.f, 0.f, 0.f, 0.f};
    f32x4 Lacc[2];
    Lacc[0] = (f32x4){0.f, 0.f, 0.f, 0.f};
    Lacc[1] = (f32x4){0.f, 0.f, 0.f, 0.f};
    const f16x4 kOnes = (f16x4){(_Float16)1.f, (_Float16)1.f, (_Float16)1.f, (_Float16)1.f};

    for (int kc = 0; kc < 16; ++kc) {
        const int buf = kc & 1;
        // ---- S^T strip: A = this wave's 16 keys, B = 32 q  (2 n-tiles)
        bf16x8 bk0 = *(const bf16x8*)(kb + (size_t)kc * 8192);
        bf16x8 bk1 = *(const bf16x8*)(kb + (size_t)kc * 8192 + 4096);
        f32x4 sacc[2];
#pragma unroll
        for (int qt2 = 0; qt2 < 2; ++qt2) {
            f32x4 s = (f32x4){0.f, 0.f, 0.f, 0.f};
            s = __builtin_amdgcn_mfma_f32_16x16x32_bf16(bk0, aq[qt2][0], s, 0, 0, 0);
            s = __builtin_amdgcn_mfma_f32_16x16x32_bf16(bk1, aq[qt2][1], s, 0, 0, 0);
            sacc[qt2] = s;
        }
        // ---- P = 2^S (scale folded into Q); pack f16; write b64 to LDS
#pragma unroll
        for (int qt2 = 0; qt2 < 2; ++qt2) {
            f16x4 ph;
#pragma unroll
            for (int r = 0; r < 4; ++r)
                ph[r] = (_Float16)__builtin_amdgcn_exp2f(sacc[qt2][r]);
            *(f16x4*)&lds.P[buf][qt2 * 16 + c][w * 16 + hi * 4] = ph;
        }
        // ---- V f16 B-frags (independent of P; drain happens at the barrier)
        const char* vcb = vb + (size_t)kc * 8192;
        f16x8 vfa0 = *(const f16x8*)(vcb);
        f16x8 vfa1 = *(const f16x8*)(vcb + 1024);
        f16x8 vfa2 = *(const f16x8*)(vcb + 2048);
        f16x8 vfa3 = *(const f16x8*)(vcb + 3072);
        f16x8 vfb0 = *(const f16x8*)(vcb + 4096);
        f16x8 vfb1 = *(const f16x8*)(vcb + 5120);
        f16x8 vfb2 = *(const f16x8*)(vcb + 6144);
        f16x8 vfb3 = *(const f16x8*)(vcb + 7168);
        __syncthreads();
        // ---- P A-frags (all 64 keys x 32 q) from LDS, b64 each
        f16x4 ap[2][4];
#pragma unroll
        for (int mt = 0; mt < 2; ++mt)
#pragma unroll
            for (int kt = 0; kt < 4; ++kt)
                ap[mt][kt] = *(const f16x4*)&lds.P[buf][mt * 16 + c][kt * 16 + hi * 4];
        // ---- U += P @ V_group(w);  L += P @ ones
#pragma unroll
        for (int mt = 0; mt < 2; ++mt) {
            Uacc[mt][0] = __builtin_amdgcn_mfma_f32_16x16x16f16(ap[mt][0], __builtin_shufflevector(vfa0, vfa0, 0, 1, 2, 3), Uacc[mt][0], 0, 0, 0);
            Uacc[mt][1] = __builtin_amdgcn_mfma_f32_16x16x16f16(ap[mt][0], __builtin_shufflevector(vfa1, vfa1, 0, 1, 2, 3), Uacc[mt][1], 0, 0, 0);
            Uacc[mt][2] = __builtin_amdgcn_mfma_f32_16x16x16f16(ap[mt][0], __builtin_shufflevector(vfa2, vfa2, 0, 1, 2, 3), Uacc[mt][2], 0, 0, 0);
            Uacc[mt][3] = __builtin_amdgcn_mfma_f32_16x16x16f16(ap[mt][0], __builtin_shufflevector(vfa3, vfa3, 0, 1, 2, 3), Uacc[mt][3], 0, 0, 0);
            Uacc[mt][0] = __builtin_amdgcn_mfma_f32_16x16x16f16(ap[mt][1], __builtin_shufflevector(vfa0, vfa0, 4, 5, 6, 7), Uacc[mt][0], 0, 0, 0);
            Uacc[mt][1] = __builtin_amdgcn_mfma_f32_16x16x16f16(ap[mt][1], __builtin_shufflevector(vfa1, vfa1, 4, 5, 6, 7), Uacc[mt][1], 0, 0, 0);
            Uacc[mt][2] = __builtin_amdgcn_mfma_f32_16x16x16f16(ap[mt][1], __builtin_shufflevector(vfa2, vfa2, 4, 5, 6, 7), Uacc[mt][2], 0, 0, 0);
            Uacc[mt][3] = __builtin_amdgcn_mfma_f32_16x16x16f16(ap[mt][1], __builtin_shufflevector(vfa3, vfa3, 4, 5, 6, 7), Uacc[mt][3], 0, 0, 0);
            Uacc[mt][0] = __builtin_amdgcn_mfma_f32_16x16x16f16(ap[mt][2], __builtin_shufflevector(vfb0, vfb0, 0, 1, 2, 3), Uacc[mt][0], 0, 0, 0);
            Uacc[mt][1] = __builtin_amdgcn_mfma_f32_16x16x16f16(ap[mt][2], __builtin_shufflevector(vfb1, vfb1, 0, 1, 2, 3), Uacc[mt][1], 0, 0, 0);
            Uacc[mt][2] = __builtin_amdgcn_mfma_f32_16x16x16f16(ap[mt][2], __builtin_shufflevector(vfb2, vfb2, 0, 1, 2, 3), Uacc[mt][2], 0, 0, 0);
            Uacc[mt][3] = __builtin_amdgcn_mfma_f32_16x16x16f16(ap[mt][2], __builtin_shufflevector(vfb3, vfb3, 0, 1, 2, 3), Uacc[mt][3], 0, 0, 0);
            Uacc[mt][0] = __builtin_amdgcn_mfma_f32_16x16x16f16(ap[mt][3], __builtin_shufflevector(vfb0, vfb0, 4, 5, 6, 7), Uacc[mt][0], 0, 0, 0);
            Uacc[mt][1] = __builtin_amdgcn_mfma_f32_16x16x16f16(ap[mt][3], __builtin_shufflevector(vfb1, vfb1, 4, 5, 6, 7), Uacc[mt][1], 0, 0, 0);
            Uacc[mt][2] = __builtin_amdgcn_mfma_f32_16x16x16f16(ap[mt][3], __builtin_shufflevector(vfb2, vfb2, 4, 5, 6, 7), Uacc[mt][2], 0, 0, 0);
            Uacc[mt][3] = __builtin_amdgcn_mfma_f32_16x16x16f16(ap[mt][3], __builtin_shufflevector(vfb3, vfb3, 4, 5, 6, 7), Uacc[mt][3], 0, 0, 0);
            Lacc[mt] = __builtin_amdgcn_mfma_f32_16x16x16f16(ap[mt][0], kOnes, Lacc[mt], 0, 0, 0);
            Lacc[mt] = __builtin_amdgcn_mfma_f32_16x16x16f16(ap[mt][1], kOnes, Lacc[mt], 0, 0, 0);
            Lacc[mt] = __builtin_amdgcn_mfma_f32_16x16x16f16(ap[mt][2], kOnes, Lacc[mt], 0, 0, 0);
            Lacc[mt] = __builtin_amdgcn_mfma_f32_16x16x16f16(ap[mt][3], kOnes, Lacc[mt], 0, 0, 0);
        }
        // dbuf: next iter writes the other buffer; barrier(kc+1) orders WAR
    }

    __syncthreads();   // all P reads done; reuse LDS as fp32 U
#pragma unroll
    for (int mt = 0; mt < 2; ++mt)
#pragma unroll
        for (int dt = 0; dt < 4; ++dt)
#pragma unroll
            for (int r = 0; r < 4; ++r)
                lds.Uf[mt * 16 + hi * 4 + r][w * 64 + dt * 16 + c] = Uacc[mt][dt][r];
    if (w == 0 && c == 0) {
#pragma unroll
        for (int mt = 0; mt < 2; ++mt)
#pragma unroll
            for (int r = 0; r < 4; ++r)
                Llds[mt * 16 + hi * 4 + r] = Lacc[mt][r];
    }
    __syncthreads();

    const float* wsf = (const float*)wsb;
    const float* nsq = wsf + (size_t)bh * 16;
    const float* vsw = wsf + 512 + (size_t)bh * 256;
    const int dd = t & 63, rq = t >> 6;
    float sg[4][4], ssum[4], omp[4], ov[4];
    const float inv22 = 1.0f / nsq[10];   // nsq[c0=2][c1=2]
#pragma unroll
    for (int gi = 0; gi < 4; ++gi) {
        float ss = 0.f, os = 0.f, ovv = 0.f;
#pragma unroll
        for (int gj = 0; gj < 4; ++gj) {
            float sgv = sqrtf(nsq[gi * 4 + gj] * inv22);
            sg[gi][gj] = sgv;
            ss += sgv;
            float om = fmaxf(1.0f - sgv, 0.0f);
            os += om;
            ovv += om * vsw[gj * 64 + dd];
        }
        ssum[gi] = ss; omp[gi] = os * 1024.0f; ov[gi] = ovv;
    }
    const size_t base = (size_t)bh * SEQ * DIM;
    float* attn_out = out + base;
    float* lse_out = out + (size_t)BH_TOT * SEQ * DIM + (size_t)bh * SEQ;
    for (int k = 0; k < 8; ++k) {
        const int r = k * 4 + rq;
        const float u0 = lds.Uf[r][dd];
        const float u1 = lds.Uf[r][64 + dd];
        const float u2 = lds.Uf[r][128 + dd];
        const float u3 = lds.Uf[r][192 + dd];
        const float Lr = Llds[r];
        const int orow = qt * 32 + r;
#pragma unroll
        for (int gi = 0; gi < 4; ++gi) {
            float num = ov[gi] + sg[gi][0] * u0 + sg[gi][1] * u1 + sg[gi][2] * u2 + sg[gi][3] * u3;
            float den = omp[gi] + ssum[gi] * Lr;
            attn_out[(size_t)(gi * 1024 + orow) * 64 + dd] = num / den;
            if (dd == gi) lse_out[gi * 1024 + orow] = __logf(den);
        }
    }
}

// ---------------- fallback path (small ws): R2 kernels ---------------------
__global__ __launch_bounds__(256) void prep_vsum(
    const float* __restrict__ value, float* __restrict__ ws)
{
    __shared__ float part[16][16][4];
    const int t = threadIdx.x;
    const int bh = blockIdx.x >> 2, gj = blockIdx.x & 3;
    const float4* vv = (const float4*)(value + ((size_t)bh * SEQ + (size_t)gj * PQ) * DIM);
    const int c4 = t & 15, rg = t >> 4;
    float a0 = 0.f, a1 = 0.f, a2 = 0.f, a3 = 0.f;
    for (int r = rg; r < 1024; r += 16) {
        float4 x = vv[r * 16 + c4];
        a0 += x.x; a1 += x.y; a2 += x.z; a3 += x.w;
    }
    part[rg][c4][0] = a0; part[rg][c4][1] = a1;
    part[rg][c4][2] = a2; part[rg][c4][3] = a3;
    __syncthreads();
    if (t < 64) {
        const int cc = t >> 2, comp = t & 3;
        float s = 0.f;
#pragma unroll
        for (int g = 0; g < 16; ++g) s += part[g][cc][comp];
        ws[512 + bh * 256 + gj * 64 + cc * 4 + comp] = s;
    }
}

__global__ __launch_bounds__(256, 2) void kattn_fallback(
    const float* __restrict__ query, const float* __restrict__ key,
    const float* __restrict__ value, const float* __restrict__ ws,
    float* __restrict__ out)
{
    __shared__ union {
        struct { short Q[64][72]; short K[64][72]; short P[64][72]; } s;
        unsigned short U[64][264];
    } lds;
    __shared__ float Llds[64];
    const int blk = blockIdx.x;
    const int bh = blk >> 4, qt = blk & 15;
    const int t = threadIdx.x;
    const int w = t >> 6, lane = t & 63;
    const int c = lane & 15, hi = lane >> 4;
    const size_t base = (size_t)bh * SEQ * DIM;
    {
        const float* qp = query + base + (size_t)(2048 + qt * 64) * DIM;
#pragma unroll
        for (int k2 = 0; k2 < 4; ++k2) {
            int u = t + k2 * 256;
            int row = u >> 4, ci = (u & 15) * 4;
            float4 qv = *(const float4*)(qp + row * 64 + ci);
            bf16x4 h;
            h[0] = f2bf(qv.x); h[1] = f2bf(qv.y); h[2] = f2bf(qv.z); h[3] = f2bf(qv.w);
            *(bf16x4*)&lds.s.Q[row][ci] = h;
        }
    }
    __syncthreads();
    bf16x8 aq0 = *(const bf16x8*)&lds.s.Q[w * 16 + c][hi * 8];
    bf16x8 aq1 = *(const bf16x8*)&lds.s.Q[w * 16 + c][32 + hi * 8];
    f32x4 Uacc[4][4];
#pragma unroll
    for (int mt = 0; mt < 4; ++mt)
#pragma unroll
        for (int nt = 0; nt < 4; ++nt)
            Uacc[mt][nt] = (f32x4){0.f, 0.f, 0.f, 0.f};
    float Lacc[4] = {0.f, 0.f, 0.f, 0.f};
    const float* kp = key + base + (size_t)2048 * DIM;
    const float* vgrp = value + base + (size_t)w * PQ * DIM;
    for (int kc = 0; kc < 16; ++kc) {
        {
            const float* kcp = kp + (size_t)kc * 64 * DIM;
#pragma unroll
            for (int k2 = 0; k2 < 4; ++k2) {
                int u = t + k2 * 256;
                int row = u >> 4, ci = (u & 15) * 4;
                float4 kv = *(const float4*)(kcp + row * 64 + ci);
                bf16x4 h;
                h[0] = f2bf(kv.x); h[1] = f2bf(kv.y); h[2] = f2bf(kv.z); h[3] = f2bf(kv.w);
                *(bf16x4*)&lds.s.K[row][ci] = h;
            }
        }
        __syncthreads();
        f32x4 sacc[4];
#pragma unroll
        for (int nt = 0; nt < 4; ++nt) sacc[nt] = (f32x4){0.f, 0.f, 0.f, 0.f};
#pragma unroll
        for (int nt = 0; nt < 4; ++nt) {
            bf16x8 bk = *(const bf16x8*)&lds.s.K[nt * 16 + c][hi * 8];
            sacc[nt] = __builtin_amdgcn_mfma_f32_16x16x32_bf16(aq0, bk, sacc[nt], 0, 0, 0);
        }
#pragma unroll
        for (int nt = 0; nt < 4; ++nt) {
            bf16x8 bk = *(const bf16x8*)&lds.s.K[nt * 16 + c][32 + hi * 8];
            sacc[nt] = __builtin_amdgcn_mfma_f32_16x16x32_bf16(aq1, bk, sacc[nt], 0, 0, 0);
        }
        float p[4][4];
#pragma unroll
        for (int nt = 0; nt < 4; ++nt)
#pragma unroll
            for (int r = 0; r < 4; ++r)
                p[nt][r] = __expf(sacc[nt][r] * 0.125f);
#pragma unroll
        for (int r = 0; r < 4; ++r) {
            float rs = p[0][r] + p[1][r] + p[2][r] + p[3][r];
            rs += __shfl_xor(rs, 1); rs += __shfl_xor(rs, 2);
            rs += __shfl_xor(rs, 4); rs += __shfl_xor(rs, 8);
            Lacc[r] += rs;
        }
#pragma unroll
        for (int nt = 0; nt < 4; ++nt)
#pragma unroll
            for (int r = 0; r < 4; ++r)
                lds.s.P[w * 16 + hi * 4 + r][nt * 16 + c] = (unsigned short)f2bf(p[nt][r]);
        __syncthreads();
        bf16x8 ap2[4][2];
#pragma unroll
        for (int mt = 0; mt < 4; ++mt) {
            ap2[mt][0] = *(const bf16x8*)&lds.s.P[mt * 16 + c][hi * 8];
            ap2[mt][1] = *(const bf16x8*)&lds.s.P[mt * 16 + c][32 + hi * 8];
        }
        const float* vp = vgrp + (size_t)kc * 64 * DIM;
#pragma unroll
        for (int kt = 0; kt < 2; ++kt) {
#pragma unroll
            for (int nt = 0; nt < 4; ++nt) {
                const float* vpp = vp + (kt * 32 + hi * 8) * 64 + nt * 16 + c;
                bf16x8 bv;
#pragma unroll
                for (int j = 0; j < 8; ++j) bv[j] = f2bf(vpp[j * 64]);
#pragma unroll
                for (int mt = 0; mt < 4; ++mt)
                    Uacc[mt][nt] = __builtin_amdgcn_mfma_f32_16x16x32_bf16(ap2[mt][kt], bv, Uacc[mt][nt], 0, 0, 0);
            }
        }
        __syncthreads();
    }
#pragma unroll
    for (int mt = 0; mt < 4; ++mt)
#pragma unroll
        for (int nt = 0; nt < 4; ++nt)
#pragma unroll
            for (int r = 0; r < 4; ++r)
                lds.U[mt * 16 + hi * 4 + r][w * 64 + nt * 16 + c] =
                    (unsigned short)f2bf(Uacc[mt][nt][r]);
    if (c == 0) {
#pragma unroll
        for (int r = 0; r < 4; ++r) Llds[w * 16 + hi * 4 + r] = Lacc[r];
    }
    __syncthreads();
    const float* nsq = ws + bh * 16;
    const float* vsw = ws + 512 + bh * 256;
    const int dd = t & 63, rq = t >> 6;
    float sg[4][4], ssum[4], omp[4], ov[4];
    const float inv22 = 1.0f / nsq[10];
#pragma unroll
    for (int gi = 0; gi < 4; ++gi) {
        float ss = 0.f, os = 0.f, ovv = 0.f;
#pragma unroll
        for (int gj = 0; gj < 4; ++gj) {
            float sgv = sqrtf(nsq[gi * 4 + gj] * inv22);
            sg[gi][gj] = sgv;
            ss += sgv;
            float om = fmaxf(1.0f - sgv, 0.0f);
            os += om;
            ovv += om * vsw[gj * 64 + dd];
        }
        ssum[gi] = ss; omp[gi] = os * 1024.0f; ov[gi] = ovv;
    }
    float* attn_out = out + base;
    float* lse_out = out + (size_t)BH_TOT * SEQ * DIM + (size_t)bh * SEQ;
    for (int k = 0; k < 16; ++k) {
        const int r = k * 4 + rq;
        const float u0 = bf2f(lds.U[r][dd]);
        const float u1 = bf2f(lds.U[r][64 + dd]);
        const float u2 = bf2f(lds.U[r][128 + dd]);
        const float u3 = bf2f(lds.U[r][192 + dd]);
        const float Lr = Llds[r];
        const int orow = qt * 64 + r;
#pragma unroll
        for (int gi = 0; gi < 4; ++gi) {
            float num = ov[gi] + sg[gi][0] * u0 + sg[gi][1] * u1 + sg[gi][2] * u2 + sg[gi][3] * u3;
            float den = omp[gi] + ssum[gi] * Lr;
            attn_out[(size_t)(gi * 1024 + orow) * 64 + dd] = num / den;
            if (dd == gi) lse_out[gi * 1024 + orow] = __logf(den);
        }
    }
}

extern "C" void kernel_launch(void* const* d_in, const int* in_sizes, int n_in,
                              void* d_out, int out_size, void* d_ws, size_t ws_size,
                              hipStream_t stream)
{
    (void)in_sizes; (void)n_in; (void)out_size;
    const float* query = (const float*)d_in[0];
    const float* key   = (const float*)d_in[1];
    const float* value = (const float*)d_in[2];
    float* ws   = (float*)d_ws;
    char*  wsb  = (char*)d_ws;
    float* outp = (float*)d_out;

    prep_norm2<<<128, 256, 0, stream>>>(query, key, ws);
    if (ws_size >= WS_NEED) {
        conv_qk<<<1024, 256, 0, stream>>>(query, key, wsb);
        conv_v<<<2048, 256, 0, stream>>>(value, wsb, ws);
        kattn3<<<1024, 256, 0, stream>>>(wsb, outp);
    } else {
        prep_vsum<<<128, 256, 0, stream>>>(value, ws);
        kattn_fallback<<<512, 256, 0, stream>>>(query, key, value, ws, outp);
    }
}

// Round 5
// 178.901 us; speedup vs baseline: 1.3932x; 1.0363x over previous
//
#include <hip/hip_runtime.h>
#include <hip/hip_bf16.h>

// KroneckerAttention on MI355X.
// B=2,H=16 (BH=32), NQ=NK=4096, D=64, m=n=4, pq=pk=1024, c0=c1=2, scale=1/8.
//
// ws layout:
//   floats [0,512)    : nsq[bh][gi][gj]
//   floats [512,8704) : vsum[bh][gj][dd]   (atomically accumulated by conv_v)
//   bytes  [34816, +4MB)  : Qb  bf16 16x16x32 B-frags, pre-scaled 0.125*log2e
//   bytes  [+4MB, +8MB)   : Kb  bf16 16x16x32 A-frags (central key group)
//   bytes  [+8MB, +24MB)  : Vb  f16  16x16x32 B-frags (all value rows)

#define BH_TOT 32
#define SEQ    4096
#define DIM    64
#define PQ     1024

#define QB_OFF 34816u
#define KB_OFF (QB_OFF + 4u*1024u*1024u)
#define VB_OFF (KB_OFF + 4u*1024u*1024u)
#define WS_NEED (VB_OFF + 16u*1024u*1024u)

#define QSCALE 0.1803368801111204f   // 0.125 * log2(e)

typedef __attribute__((ext_vector_type(8))) short bf16x8;
typedef __attribute__((ext_vector_type(4))) short bf16x4;
typedef __attribute__((ext_vector_type(4))) float f32x4;
typedef __attribute__((ext_vector_type(4))) _Float16 f16x4;
typedef __attribute__((ext_vector_type(8))) _Float16 f16x8;

__device__ __forceinline__ short f2bf(float x) {
    unsigned u = __float_as_uint(x);
    u = u + 0x7fffu + ((u >> 16) & 1u);   // RNE truncate to bf16
    return (short)(u >> 16);
}
__device__ __forceinline__ float bf2f(unsigned short h) {
    return __uint_as_float(((unsigned)h) << 16);
}

// ---------------- prep_norm2: 128 blocks (bh,gi) -> nsq via MFMA -----------
// Also zero-inits vsum (conv_v accumulates into it later in stream order).
__global__ __launch_bounds__(256) void prep_norm2(
    const float* __restrict__ query, const float* __restrict__ key,
    float* __restrict__ ws)
{
    __shared__ float ksm[4][64];
    __shared__ float wsum[4][16];
    const int t = threadIdx.x;
    const int bh = blockIdx.x >> 2, gi = blockIdx.x & 3;
    if (t < 64) ws[512 + blockIdx.x * 64 + t] = 0.f;   // 128*64 = 8192 = vsum
    ksm[t >> 6][t & 63] = key[((size_t)bh * SEQ + (size_t)(t >> 6) * PQ) * DIM + (t & 63)];
    __syncthreads();
    const int wv = t >> 6, lane = t & 63, c = lane & 15, hi = lane >> 4;
    bf16x8 bb0, bb1;
#pragma unroll
    for (int j = 0; j < 8; ++j) {
        bb0[j] = (c < 4) ? f2bf(ksm[c][hi * 8 + j]) : (short)0;
        bb1[j] = (c < 4) ? f2bf(ksm[c][32 + hi * 8 + j]) : (short)0;
    }
    float acc0 = 0.f, acc1 = 0.f, acc2 = 0.f, acc3 = 0.f;
    const float* qbase = query + ((size_t)bh * SEQ + (size_t)gi * PQ) * DIM;
    for (int it = 0; it < 16; ++it) {
        const int row = (wv * 16 + it) * 16 + c;
        const float* qp = qbase + (size_t)row * 64 + hi * 8;
        float4 a0 = *(const float4*)qp;
        float4 a1 = *(const float4*)(qp + 4);
        float4 a2 = *(const float4*)(qp + 32);
        float4 a3 = *(const float4*)(qp + 36);
        bf16x8 qa0, qa1;
        qa0[0] = f2bf(a0.x); qa0[1] = f2bf(a0.y); qa0[2] = f2bf(a0.z); qa0[3] = f2bf(a0.w);
        qa0[4] = f2bf(a1.x); qa0[5] = f2bf(a1.y); qa0[6] = f2bf(a1.z); qa0[7] = f2bf(a1.w);
        qa1[0] = f2bf(a2.x); qa1[1] = f2bf(a2.y); qa1[2] = f2bf(a2.z); qa1[3] = f2bf(a2.w);
        qa1[4] = f2bf(a3.x); qa1[5] = f2bf(a3.y); qa1[6] = f2bf(a3.z); qa1[7] = f2bf(a3.w);
        f32x4 s = (f32x4){0.f, 0.f, 0.f, 0.f};
        s = __builtin_amdgcn_mfma_f32_16x16x32_bf16(qa0, bb0, s, 0, 0, 0);
        s = __builtin_amdgcn_mfma_f32_16x16x32_bf16(qa1, bb1, s, 0, 0, 0);
        acc0 += s[0] * s[0]; acc1 += s[1] * s[1];
        acc2 += s[2] * s[2]; acc3 += s[3] * s[3];
    }
    float asum = acc0 + acc1 + acc2 + acc3;
    asum += __shfl_xor(asum, 16);
    asum += __shfl_xor(asum, 32);
    if (lane < 16) wsum[wv][lane] = asum;
    __syncthreads();
    if (t < 4) ws[bh * 16 + gi * 4 + t] = wsum[0][t] + wsum[1][t] + wsum[2][t] + wsum[3][t];
}

// ---------------- conv_qk: blocks [0,512) Q-frags, [512,1024) K-frags ------
__global__ __launch_bounds__(256) void conv_qk(
    const float* __restrict__ query, const float* __restrict__ key,
    char* __restrict__ wsb)
{
    const int t = threadIdx.x;
    if (blockIdx.x < 512) {
        const int bh = blockIdx.x >> 4, qt = blockIdx.x & 15;
#pragma unroll
        for (int i = 0; i < 2; ++i) {
            const int sid = t + i * 256;
            const int mt = sid >> 7, kh = (sid >> 6) & 1, lane = sid & 63;
            const int c = lane & 15, hi = lane >> 4;
            const float* p = query + ((size_t)bh * SEQ + 2048 + qt * 64 + mt * 16 + c) * DIM
                             + kh * 32 + hi * 8;
            float4 a = *(const float4*)p, b = *(const float4*)(p + 4);
            bf16x8 h;
            h[0] = f2bf(a.x * QSCALE); h[1] = f2bf(a.y * QSCALE);
            h[2] = f2bf(a.z * QSCALE); h[3] = f2bf(a.w * QSCALE);
            h[4] = f2bf(b.x * QSCALE); h[5] = f2bf(b.y * QSCALE);
            h[6] = f2bf(b.z * QSCALE); h[7] = f2bf(b.w * QSCALE);
            const size_t fidx = ((size_t)(bh * 16 + qt) * 4 + mt) * 2 + kh;
            *(bf16x8*)(wsb + QB_OFF + fidx * 1024 + lane * 16) = h;
        }
    } else {
        const int b2 = blockIdx.x - 512;
        const int bh = b2 >> 4, kc = b2 & 15;
#pragma unroll
        for (int i = 0; i < 2; ++i) {
            const int sid = t + i * 256;
            const int kh = sid >> 8, nt = (sid >> 6) & 3, lane = sid & 63;
            const int c = lane & 15, hi = lane >> 4;
            const float* p = key + ((size_t)bh * SEQ + 2048 + kc * 64 + nt * 16 + c) * DIM
                             + kh * 32 + hi * 8;
            float4 a = *(const float4*)p, b = *(const float4*)(p + 4);
            bf16x8 h;
            h[0] = f2bf(a.x); h[1] = f2bf(a.y); h[2] = f2bf(a.z); h[3] = f2bf(a.w);
            h[4] = f2bf(b.x); h[5] = f2bf(b.y); h[6] = f2bf(b.z); h[7] = f2bf(b.w);
            const size_t fidx = ((size_t)(bh * 16 + kc) * 2 + kh) * 4 + nt;
            *(bf16x8*)(wsb + KB_OFF + fidx * 1024 + lane * 16) = h;
        }
    }
}

// ------- conv_v: 2048 blocks (bh,gj,kc) -> f16 16x16x32 B-frags + vsum -----
__global__ __launch_bounds__(256) void conv_v(
    const float* __restrict__ value, char* __restrict__ wsb, float* __restrict__ ws)
{
    __shared__ float Ls[64][68];
    __shared__ float ps[4][64];
    const int t = threadIdx.x;
    const int blk = blockIdx.x;
    const int bh = blk >> 6, gj = (blk >> 4) & 3, kc = blk & 15;
    const float* src = value + ((size_t)bh * SEQ + gj * PQ + kc * 64) * DIM;
#pragma unroll
    for (int i = 0; i < 4; ++i) {
        const int u = t + i * 256;
        const int row = u >> 4, c4 = (u & 15) * 4;
        *(float4*)&Ls[row][c4] = *(const float4*)(src + row * 64 + c4);
    }
    __syncthreads();
    {
        const int d = t & 63, rg = t >> 6;
        float s = 0.f;
#pragma unroll
        for (int i = 0; i < 16; ++i) s += Ls[rg * 16 + i][d];
        ps[rg][d] = s;
    }
    __syncthreads();
    if (t < 64) {
        float tot = ps[0][t] + ps[1][t] + ps[2][t] + ps[3][t];
        atomicAdd(&ws[512 + bh * 256 + gj * 64 + t], tot);
    }
    // 16x16x32 f16 B-frags: lane(c,hi) holds V[span*32 + hi*8 + j][dt*16 + c]
#pragma unroll
    for (int i = 0; i < 2; ++i) {
        const int sid = t + i * 256;
        const int pl = sid >> 8, dt = (sid >> 6) & 3, lane = sid & 63;
        const int c = lane & 15, hi = lane >> 4;
        f16x8 h;
#pragma unroll
        for (int j = 0; j < 8; ++j)
            h[j] = (_Float16)Ls[pl * 32 + hi * 8 + j][dt * 16 + c];
        const size_t off = ((((size_t)(bh * 4 + gj) * 32 + kc * 2 + pl) * 4 + dt) * 64 + lane) * 16;
        *(f16x8*)(wsb + VB_OFF + off) = h;
    }
}

// ---------------- kattn4: S^T attention, frag-layout P, XCD-swizzled -------
// grid = 1024, block = 256 (4 waves). Swizzle: all 32 q-tiles of a bh land on
// one XCD (assuming XCD = blockIdx % 8) so K/V frags stay in that L2.
__global__ __launch_bounds__(256, 4) void kattn4(
    const char* __restrict__ wsb, float* __restrict__ out)
{
    __shared__ union {
        _Float16 Pf[2][2][2][512];  // [buf][mt][span][frag] — A-frag order
        float Uf[32][257];          // epilogue: fp32 U (4 groups x 64 d)
    } lds;
    __shared__ float Llds[32];

    const int blk = blockIdx.x;
    const int slot = blk >> 3;
    const int bh = (blk & 7) * 4 + (slot >> 5);   // XCD-major
    const int qt = slot & 31;
    const int t = threadIdx.x;
    const int w = t >> 6, lane = t & 63;
    const int c = lane & 15, hi = lane >> 4;

    // Q B-frags (pre-scaled): strips s = qt*2 + qt2
    bf16x8 aq[2][2];
#pragma unroll
    for (int qt2 = 0; qt2 < 2; ++qt2) {
        const int s = qt * 2 + qt2;
        const size_t fr = ((size_t)(bh * 16 + (s >> 2)) * 4 + (s & 3)) * 2;
        aq[qt2][0] = *(const bf16x8*)(wsb + QB_OFF + fr * 1024 + lane * 16);
        aq[qt2][1] = *(const bf16x8*)(wsb + QB_OFF + (fr + 1) * 1024 + lane * 16);
    }
    const char* kb = wsb + KB_OFF + ((size_t)(bh * 16) * 8) * 1024 + (size_t)w * 1024 + lane * 16;
    const char* vb = wsb + VB_OFF + ((size_t)(bh * 4 + w) * 128) * 1024 + lane * 16;

    f32x4 Uacc[2][4];
#pragma unroll
    for (int mt = 0; mt < 2; ++mt)
#pragma unroll
        for (int dt = 0; dt < 4; ++dt)
            Uacc[mt][dt] = (f32x4){0.f, 0.f, 0.f, 0.f};
    f32x4 Lacc[2];
    Lacc[0] = (f32x4){0.f, 0.f, 0.f, 0.f};
    Lacc[1] = (f32x4){0.f, 0.f, 0.f, 0.f};
    f16x8 kOnes;
#pragma unroll
    for (int j = 0; j < 8; ++j) kOnes[j] = (_Float16)1.f;

    // P write coords (A-frag order): element (m=c, k=w*16+hi*4+r)
    const int k0 = w * 16 + hi * 4;
    const int pspan = k0 >> 5;                    // w>>1
    const int pidx = (c + 16 * ((k0 & 31) >> 3)) * 8 + (k0 & 7);  // b64 dest

    bf16x8 bk0 = *(const bf16x8*)(kb);
    bf16x8 bk1 = *(const bf16x8*)(kb + 4096);

    for (int kc = 0; kc < 16; ++kc) {
        const int buf = kc & 1;
        // ---- S^T strip: A = this wave's 16 keys, B = 32 q (2 tiles)
        f32x4 sacc[2];
#pragma unroll
        for (int qt2 = 0; qt2 < 2; ++qt2) {
            f32x4 s = (f32x4){0.f, 0.f, 0.f, 0.f};
            s = __builtin_amdgcn_mfma_f32_16x16x32_bf16(bk0, aq[qt2][0], s, 0, 0, 0);
            s = __builtin_amdgcn_mfma_f32_16x16x32_bf16(bk1, aq[qt2][1], s, 0, 0, 0);
            sacc[qt2] = s;
        }
        // ---- P = 2^S -> f16 -> LDS in A-frag order (b64, <=2-way banks)
#pragma unroll
        for (int qt2 = 0; qt2 < 2; ++qt2) {
            f16x4 ph;
#pragma unroll
            for (int r = 0; r < 4; ++r)
                ph[r] = (_Float16)__builtin_amdgcn_exp2f(sacc[qt2][r]);
            *(f16x4*)&lds.Pf[buf][qt2][pspan][pidx] = ph;
        }
        // ---- prefetch V(kc) and K(kc+1); barrier's vmcnt drain covers both
        const char* vcb = vb + (size_t)kc * 8192;
        f16x8 vf[8];
#pragma unroll
        for (int u = 0; u < 8; ++u) vf[u] = *(const f16x8*)(vcb + u * 1024);
        if (kc < 15) {
            bk0 = *(const bf16x8*)(kb + (size_t)(kc + 1) * 8192);
            bk1 = *(const bf16x8*)(kb + (size_t)(kc + 1) * 8192 + 4096);
        }
        __syncthreads();
        // ---- P A-frags: stride-1 b128 reads (conflict-free)
        f16x8 ap[2][2];
#pragma unroll
        for (int mt = 0; mt < 2; ++mt)
#pragma unroll
            for (int sp = 0; sp < 2; ++sp)
                ap[mt][sp] = *(const f16x8*)&lds.Pf[buf][mt][sp][lane * 8];
        // ---- U += P @ V_group(w) (16x16x32 f16); L += P @ ones
#pragma unroll
        for (int mt = 0; mt < 2; ++mt) {
#pragma unroll
            for (int sp = 0; sp < 2; ++sp) {
                Uacc[mt][0] = __builtin_amdgcn_mfma_f32_16x16x32_f16(ap[mt][sp], vf[sp * 4 + 0], Uacc[mt][0], 0, 0, 0);
                Uacc[mt][1] = __builtin_amdgcn_mfma_f32_16x16x32_f16(ap[mt][sp], vf[sp * 4 + 1], Uacc[mt][1], 0, 0, 0);
                Uacc[mt][2] = __builtin_amdgcn_mfma_f32_16x16x32_f16(ap[mt][sp], vf[sp * 4 + 2], Uacc[mt][2], 0, 0, 0);
                Uacc[mt][3] = __builtin_amdgcn_mfma_f32_16x16x32_f16(ap[mt][sp], vf[sp * 4 + 3], Uacc[mt][3], 0, 0, 0);
                Lacc[mt]    = __builtin_amdgcn_mfma_f32_16x16x32_f16(ap[mt][sp], kOnes, Lacc[mt], 0, 0, 0);
            }
        }
        // dbuf: next iter writes the other buffer; its barrier orders WAR
    }

    __syncthreads();   // all P reads done; reuse LDS as fp32 U
#pragma unroll
    for (int mt = 0; mt < 2; ++mt)
#pragma unroll
        for (int dt = 0; dt < 4; ++dt)
#pragma unroll
            for (int r = 0; r < 4; ++r)
                lds.Uf[mt * 16 + hi * 4 + r][w * 64 + dt * 16 + c] = Uacc[mt][dt][r];
    if (w == 0 && c == 0) {
#pragma unroll
        for (int mt = 0; mt < 2; ++mt)
#pragma unroll
            for (int r = 0; r < 4; ++r)
                Llds[mt * 16 + hi * 4 + r] = Lacc[mt][r];
    }
    __syncthreads();

    const float* wsf = (const float*)wsb;
    const float* nsq = wsf + (size_t)bh * 16;
    const float* vsw = wsf + 512 + (size_t)bh * 256;
    const int dd = t & 63, rq = t >> 6;
    float sg[4][4], ssum[4], omp[4], ov[4];
    const float inv22 = 1.0f / nsq[10];   // nsq[c0=2][c1=2]
#pragma unroll
    for (int gi = 0; gi < 4; ++gi) {
        float ss = 0.f, os = 0.f, ovv = 0.f;
#pragma unroll
        for (int gj = 0; gj < 4; ++gj) {
            float sgv = sqrtf(nsq[gi * 4 + gj] * inv22);
            sg[gi][gj] = sgv;
            ss += sgv;
            float om = fmaxf(1.0f - sgv, 0.0f);
            os += om;
            ovv += om * vsw[gj * 64 + dd];
        }
        ssum[gi] = ss; omp[gi] = os * 1024.0f; ov[gi] = ovv;
    }
    const size_t base = (size_t)bh * SEQ * DIM;
    float* attn_out = out + base;
    float* lse_out = out + (size_t)BH_TOT * SEQ * DIM + (size_t)bh * SEQ;
    for (int k = 0; k < 8; ++k) {
        const int r = k * 4 + rq;
        const float u0 = lds.Uf[r][dd];
        const float u1 = lds.Uf[r][64 + dd];
        const float u2 = lds.Uf[r][128 + dd];
        const float u3 = lds.Uf[r][192 + dd];
        const float Lr = Llds[r];
        const int orow = qt * 32 + r;
#pragma unroll
        for (int gi = 0; gi < 4; ++gi) {
            float num = ov[gi] + sg[gi][0] * u0 + sg[gi][1] * u1 + sg[gi][2] * u2 + sg[gi][3] * u3;
            float den = omp[gi] + ssum[gi] * Lr;
            attn_out[(size_t)(gi * 1024 + orow) * 64 + dd] = num / den;
            if (dd == gi) lse_out[gi * 1024 + orow] = __logf(den);
        }
    }
}

// ---------------- fallback path (small ws): R2 kernels ---------------------
__global__ __launch_bounds__(256) void prep_vsum(
    const float* __restrict__ value, float* __restrict__ ws)
{
    __shared__ float part[16][16][4];
    const int t = threadIdx.x;
    const int bh = blockIdx.x >> 2, gj = blockIdx.x & 3;
    const float4* vv = (const float4*)(value + ((size_t)bh * SEQ + (size_t)gj * PQ) * DIM);
    const int c4 = t & 15, rg = t >> 4;
    float a0 = 0.f, a1 = 0.f, a2 = 0.f, a3 = 0.f;
    for (int r = rg; r < 1024; r += 16) {
        float4 x = vv[r * 16 + c4];
        a0 += x.x; a1 += x.y; a2 += x.z; a3 += x.w;
    }
    part[rg][c4][0] = a0; part[rg][c4][1] = a1;
    part[rg][c4][2] = a2; part[rg][c4][3] = a3;
    __syncthreads();
    if (t < 64) {
        const int cc = t >> 2, comp = t & 3;
        float s = 0.f;
#pragma unroll
        for (int g = 0; g < 16; ++g) s += part[g][cc][comp];
        ws[512 + bh * 256 + gj * 64 + cc * 4 + comp] = s;
    }
}

__global__ __launch_bounds__(256, 2) void kattn_fallback(
    const float* __restrict__ query, const float* __restrict__ key,
    const float* __restrict__ value, const float* __restrict__ ws,
    float* __restrict__ out)
{
    __shared__ union {
        struct { short Q[64][72]; short K[64][72]; short P[64][72]; } s;
        unsigned short U[64][264];
    } lds;
    __shared__ float Llds[64];
    const int blk = blockIdx.x;
    const int bh = blk >> 4, qt = blk & 15;
    const int t = threadIdx.x;
    const int w = t >> 6, lane = t & 63;
    const int c = lane & 15, hi = lane >> 4;
    const size_t base = (size_t)bh * SEQ * DIM;
    {
        const float* qp = query + base + (size_t)(2048 + qt * 64) * DIM;
#pragma unroll
        for (int k2 = 0; k2 < 4; ++k2) {
            int u = t + k2 * 256;
            int row = u >> 4, ci = (u & 15) * 4;
            float4 qv = *(const float4*)(qp + row * 64 + ci);
            bf16x4 h;
            h[0] = f2bf(qv.x); h[1] = f2bf(qv.y); h[2] = f2bf(qv.z); h[3] = f2bf(qv.w);
            *(bf16x4*)&lds.s.Q[row][ci] = h;
        }
    }
    __syncthreads();
    bf16x8 aq0 = *(const bf16x8*)&lds.s.Q[w * 16 + c][hi * 8];
    bf16x8 aq1 = *(const bf16x8*)&lds.s.Q[w * 16 + c][32 + hi * 8];
    f32x4 Uacc[4][4];
#pragma unroll
    for (int mt = 0; mt < 4; ++mt)
#pragma unroll
        for (int nt = 0; nt < 4; ++nt)
            Uacc[mt][nt] = (f32x4){0.f, 0.f, 0.f, 0.f};
    float Lacc[4] = {0.f, 0.f, 0.f, 0.f};
    const float* kp = key + base + (size_t)2048 * DIM;
    const float* vgrp = value + base + (size_t)w * PQ * DIM;
    for (int kc = 0; kc < 16; ++kc) {
        {
            const float* kcp = kp + (size_t)kc * 64 * DIM;
#pragma unroll
            for (int k2 = 0; k2 < 4; ++k2) {
                int u = t + k2 * 256;
                int row = u >> 4, ci = (u & 15) * 4;
                float4 kv = *(const float4*)(kcp + row * 64 + ci);
                bf16x4 h;
                h[0] = f2bf(kv.x); h[1] = f2bf(kv.y); h[2] = f2bf(kv.z); h[3] = f2bf(kv.w);
                *(bf16x4*)&lds.s.K[row][ci] = h;
            }
        }
        __syncthreads();
        f32x4 sacc[4];
#pragma unroll
        for (int nt = 0; nt < 4; ++nt) sacc[nt] = (f32x4){0.f, 0.f, 0.f, 0.f};
#pragma unroll
        for (int nt = 0; nt < 4; ++nt) {
            bf16x8 bk = *(const bf16x8*)&lds.s.K[nt * 16 + c][hi * 8];
            sacc[nt] = __builtin_amdgcn_mfma_f32_16x16x32_bf16(aq0, bk, sacc[nt], 0, 0, 0);
        }
#pragma unroll
        for (int nt = 0; nt < 4; ++nt) {
            bf16x8 bk = *(const bf16x8*)&lds.s.K[nt * 16 + c][32 + hi * 8];
            sacc[nt] = __builtin_amdgcn_mfma_f32_16x16x32_bf16(aq1, bk, sacc[nt], 0, 0, 0);
        }
        float p[4][4];
#pragma unroll
        for (int nt = 0; nt < 4; ++nt)
#pragma unroll
            for (int r = 0; r < 4; ++r)
                p[nt][r] = __expf(sacc[nt][r] * 0.125f);
#pragma unroll
        for (int r = 0; r < 4; ++r) {
            float rs = p[0][r] + p[1][r] + p[2][r] + p[3][r];
            rs += __shfl_xor(rs, 1); rs += __shfl_xor(rs, 2);
            rs += __shfl_xor(rs, 4); rs += __shfl_xor(rs, 8);
            Lacc[r] += rs;
        }
#pragma unroll
        for (int nt = 0; nt < 4; ++nt)
#pragma unroll
            for (int r = 0; r < 4; ++r)
                lds.s.P[w * 16 + hi * 4 + r][nt * 16 + c] = (unsigned short)f2bf(p[nt][r]);
        __syncthreads();
        bf16x8 ap2[4][2];
#pragma unroll
        for (int mt = 0; mt < 4; ++mt) {
            ap2[mt][0] = *(const bf16x8*)&lds.s.P[mt * 16 + c][hi * 8];
            ap2[mt][1] = *(const bf16x8*)&lds.s.P[mt * 16 + c][32 + hi * 8];
        }
        const float* vp = vgrp + (size_t)kc * 64 * DIM;
#pragma unroll
        for (int kt = 0; kt < 2; ++kt) {
#pragma unroll
            for (int nt = 0; nt < 4; ++nt) {
                const float* vpp = vp + (kt * 32 + hi * 8) * 64 + nt * 16 + c;
                bf16x8 bv;
#pragma unroll
                for (int j = 0; j < 8; ++j) bv[j] = f2bf(vpp[j * 64]);
#pragma unroll
                for (int mt = 0; mt < 4; ++mt)
                    Uacc[mt][nt] = __builtin_amdgcn_mfma_f32_16x16x32_bf16(ap2[mt][kt], bv, Uacc[mt][nt], 0, 0, 0);
            }
        }
        __syncthreads();
    }
#pragma unroll
    for (int mt = 0; mt < 4; ++mt)
#pragma unroll
        for (int nt = 0; nt < 4; ++nt)
#pragma unroll
            for (int r = 0; r < 4; ++r)
                lds.U[mt * 16 + hi * 4 + r][w * 64 + nt * 16 + c] =
                    (unsigned short)f2bf(Uacc[mt][nt][r]);
    if (c == 0) {
#pragma unroll
        for (int r = 0; r < 4; ++r) Llds[w * 16 + hi * 4 + r] = Lacc[r];
    }
    __syncthreads();
    const float* nsq = ws + bh * 16;
    const float* vsw = ws + 512 + bh * 256;
    const int dd = t & 63, rq = t >> 6;
    float sg[4][4], ssum[4], omp[4], ov[4];
    const float inv22 = 1.0f / nsq[10];
#pragma unroll
    for (int gi = 0; gi < 4; ++gi) {
        float ss = 0.f, os = 0.f, ovv = 0.f;
#pragma unroll
        for (int gj = 0; gj < 4; ++gj) {
            float sgv = sqrtf(nsq[gi * 4 + gj] * inv22);
            sg[gi][gj] = sgv;
            ss += sgv;
            float om = fmaxf(1.0f - sgv, 0.0f);
            os += om;
            ovv += om * vsw[gj * 64 + dd];
        }
        ssum[gi] = ss; omp[gi] = os * 1024.0f; ov[gi] = ovv;
    }
    float* attn_out = out + base;
    float* lse_out = out + (size_t)BH_TOT * SEQ * DIM + (size_t)bh * SEQ;
    for (int k = 0; k < 16; ++k) {
        const int r = k * 4 + rq;
        const float u0 = bf2f(lds.U[r][dd]);
        const float u1 = bf2f(lds.U[r][64 + dd]);
        const float u2 = bf2f(lds.U[r][128 + dd]);
        const float u3 = bf2f(lds.U[r][192 + dd]);
        const float Lr = Llds[r];
        const int orow = qt * 64 + r;
#pragma unroll
        for (int gi = 0; gi < 4; ++gi) {
            float num = ov[gi] + sg[gi][0] * u0 + sg[gi][1] * u1 + sg[gi][2] * u2 + sg[gi][3] * u3;
            float den = omp[gi] + ssum[gi] * Lr;
            attn_out[(size_t)(gi * 1024 + orow) * 64 + dd] = num / den;
            if (dd == gi) lse_out[gi * 1024 + orow] = __logf(den);
        }
    }
}

extern "C" void kernel_launch(void* const* d_in, const int* in_sizes, int n_in,
                              void* d_out, int out_size, void* d_ws, size_t ws_size,
                              hipStream_t stream)
{
    (void)in_sizes; (void)n_in; (void)out_size;
    const float* query = (const float*)d_in[0];
    const float* key   = (const float*)d_in[1];
    const float* value = (const float*)d_in[2];
    float* ws   = (float*)d_ws;
    char*  wsb  = (char*)d_ws;
    float* outp = (float*)d_out;

    prep_norm2<<<128, 256, 0, stream>>>(query, key, ws);
    if (ws_size >= WS_NEED) {
        conv_qk<<<1024, 256, 0, stream>>>(query, key, wsb);
        conv_v<<<2048, 256, 0, stream>>>(value, wsb, ws);
        kattn4<<<1024, 256, 0, stream>>>(wsb, outp);
    } else {
        prep_vsum<<<128, 256, 0, stream>>>(value, ws);
        kattn_fallback<<<512, 256, 0, stream>>>(query, key, value, ws, outp);
    }
}